// Round 1
// baseline (228.571 us; speedup 1.0000x reference)
//
#include <hip/hip_runtime.h>
#include <hip/hip_bf16.h>
#include <cstdint>
#include <cstddef>

// SlideAttention fused pipeline for MI355X (gfx950).
// B=8, H=W=64, C=256, HEADS=8, U=32, WIN=3 (9 taps), CPB=512.
//
// Stages:
//  k_setup     : rel_bias[8][9] via CPB MLP, exp(scale)[8]
//  k_transpose : dk (3,3,256,9) -> dkt[(tap*9+m)*256+c] f32 ;
//                w_qkv (256,768) -> wT[n][k] bf16 ; proj_w -> pT[n][k] bf16
//  k_qkv_gemm  : qkv[pix][768] bf16 = x @ w_qkv + bias   (MFMA bf16)
//  k_attn      : fused slide-conv (k,v) + cosine attn -> att[pix][256] bf16
//  k_proj_gemm : out = att @ proj_w + proj_b (f32)       (MFMA bf16)

typedef __attribute__((ext_vector_type(4))) float f32x4;
typedef __attribute__((ext_vector_type(8))) short s16x8;
typedef __attribute__((ext_vector_type(4))) int   i32x4;

#define DEVINL __device__ __forceinline__

DEVINL float bf2f(unsigned short h) {
    unsigned int u = ((unsigned int)h) << 16;
    return __builtin_bit_cast(float, u);
}
DEVINL unsigned short f2bf(float f) {  // RNE, finite inputs only
    unsigned int u = __builtin_bit_cast(unsigned int, f);
    u += 0x7FFFu + ((u >> 16) & 1u);
    return (unsigned short)(u >> 16);
}
// LDS xor-swizzle: rows are 128 B; xor row&7 into byte-bits 4..6 (16B units)
DEVINL int swz(int off) { return off ^ ((off >> 3) & 0x70); }

// ---------------------------------------------------------------- setup ----
__global__ void k_setup(const float* __restrict__ scale,
                        const float* __restrict__ w1,
                        const float* __restrict__ b1,
                        const float* __restrict__ w2,
                        float* __restrict__ relb,
                        float* __restrict__ escale) {
    int t = threadIdx.x;
    if (t < 72) {
        int m = t / 8, head = t % 8;
        float dy = (float)(m / 3 - 1), dx = (float)(m % 3 - 1);
        const float il8 = 0.48089834696298783f; // 1/ln(8)
        float r0 = (dy > 0.f ? 1.f : (dy < 0.f ? -1.f : 0.f)) * log1pf(fabsf(dy)) * il8;
        float r1 = (dx > 0.f ? 1.f : (dx < 0.f ? -1.f : 0.f)) * log1pf(fabsf(dx)) * il8;
        float acc = 0.f;
        for (int j = 0; j < 512; ++j) {
            float h = fmaxf(r0 * w1[j] + r1 * w1[512 + j] + b1[j], 0.f);
            acc += h * w2[j * 8 + head];
        }
        relb[head * 9 + m] = 16.f / (1.f + expf(-acc));
    } else if (t < 80) {
        escale[t - 72] = expf(scale[t - 72]);
    }
}

// ------------------------------------------------------------ transpose ----
__global__ void k_transpose(const float* __restrict__ dk,
                            const float* __restrict__ wq,
                            const float* __restrict__ pw,
                            float* __restrict__ dkt,
                            unsigned short* __restrict__ wT,
                            unsigned short* __restrict__ pT) {
    int i = blockIdx.x * blockDim.x + threadIdx.x;
    if (i < 20736) {                    // dkt[(tap*9+m)*256+c] = dk[tap][c][m]
        int l = i >> 8, c = i & 255;
        int tap = l / 9, m = l % 9;
        dkt[i] = dk[(tap * 256 + c) * 9 + m];
        return;
    }
    int j = i - 20736;
    if (j < 196608) {                   // wT[n*256+k] = bf16(wq[k*768+n])
        int n = j >> 8, k = j & 255;
        wT[j] = f2bf(wq[k * 768 + n]);
        return;
    }
    int p = j - 196608;
    if (p < 65536) {                    // pT[n*256+k] = bf16(pw[k*256+n])
        int n = p >> 8, k = p & 255;
        pT[p] = f2bf(pw[k * 256 + n]);
    }
}

// ------------------------------------------------------------- qkv GEMM ----
// 128x256 tile, 512 threads (8 waves, 2x4), wave does 64x64 via 4x4 16x16x32.
__launch_bounds__(512, 1)
__global__ void k_qkv_gemm(const float* __restrict__ x,
                           const unsigned short* __restrict__ wT,
                           const float* __restrict__ qb,
                           const float* __restrict__ vb,
                           unsigned short* __restrict__ qkv) {
    __shared__ __align__(16) unsigned short As[128 * 64];
    __shared__ __align__(16) unsigned short Bs[256 * 64];
    const int t = threadIdx.x;
    const int m0 = blockIdx.x * 128;
    const int n0 = blockIdx.y * 256;
    const int wid = t >> 6, lane = t & 63;
    const int wm = wid >> 2, wn = wid & 3;
    const int lr = lane & 15, lk = lane >> 4;
    const int ar = t >> 2, aq = t & 3;    // A staging: row, 16-float quarter
    const int bn = t >> 1, bh = t & 1;    // B staging: n-row, 32-elem half
    f32x4 acc[4][4] = {};

    for (int ks = 0; ks < 256; ks += 64) {
        {   // stage A (f32 -> bf16)
            const float* src = x + (size_t)(m0 + ar) * 256 + ks + aq * 16;
            f32x4 v0 = *(const f32x4*)(src + 0);
            f32x4 v1 = *(const f32x4*)(src + 4);
            f32x4 v2 = *(const f32x4*)(src + 8);
            f32x4 v3 = *(const f32x4*)(src + 12);
            s16x8 h0, h1;
            h0[0]=(short)f2bf(v0[0]); h0[1]=(short)f2bf(v0[1]); h0[2]=(short)f2bf(v0[2]); h0[3]=(short)f2bf(v0[3]);
            h0[4]=(short)f2bf(v1[0]); h0[5]=(short)f2bf(v1[1]); h0[6]=(short)f2bf(v1[2]); h0[7]=(short)f2bf(v1[3]);
            h1[0]=(short)f2bf(v2[0]); h1[1]=(short)f2bf(v2[1]); h1[2]=(short)f2bf(v2[2]); h1[3]=(short)f2bf(v2[3]);
            h1[4]=(short)f2bf(v3[0]); h1[5]=(short)f2bf(v3[1]); h1[6]=(short)f2bf(v3[2]); h1[7]=(short)f2bf(v3[3]);
            int off = ar * 128 + aq * 32;
            *(s16x8*)((char*)As + swz(off))      = h0;
            *(s16x8*)((char*)As + swz(off + 16)) = h1;
        }
        {   // stage B (already bf16, K-major)
            const unsigned short* src = wT + (size_t)(n0 + bn) * 256 + ks + bh * 32;
            s16x8 b0 = *(const s16x8*)(src + 0);
            s16x8 b1 = *(const s16x8*)(src + 8);
            s16x8 b2 = *(const s16x8*)(src + 16);
            s16x8 b3 = *(const s16x8*)(src + 24);
            int off = bn * 128 + bh * 64;
            *(s16x8*)((char*)Bs + swz(off))      = b0;
            *(s16x8*)((char*)Bs + swz(off + 16)) = b1;
            *(s16x8*)((char*)Bs + swz(off + 32)) = b2;
            *(s16x8*)((char*)Bs + swz(off + 48)) = b3;
        }
        __syncthreads();
        #pragma unroll
        for (int kc = 0; kc < 2; ++kc) {
            s16x8 af[4], bfr[4];
            #pragma unroll
            for (int i = 0; i < 4; ++i) {
                int off = (wm * 64 + i * 16 + lr) * 128 + kc * 64 + lk * 16;
                af[i] = *(const s16x8*)((const char*)As + swz(off));
            }
            #pragma unroll
            for (int i = 0; i < 4; ++i) {
                int off = (wn * 64 + i * 16 + lr) * 128 + kc * 64 + lk * 16;
                bfr[i] = *(const s16x8*)((const char*)Bs + swz(off));
            }
            #pragma unroll
            for (int i = 0; i < 4; ++i)
                #pragma unroll
                for (int j = 0; j < 4; ++j)
                    acc[i][j] = __builtin_amdgcn_mfma_f32_16x16x32_bf16(af[i], bfr[j], acc[i][j], 0, 0, 0);
        }
        __syncthreads();
    }
    #pragma unroll
    for (int i = 0; i < 4; ++i) {
        const int mg = m0 + wm * 64 + i * 16 + lk * 4;
        #pragma unroll
        for (int j = 0; j < 4; ++j) {
            const int ng = n0 + wn * 64 + j * 16 + lr;
            float bias = (ng < 256) ? qb[ng] : ((ng < 512) ? 0.f : vb[ng - 512]);
            #pragma unroll
            for (int e = 0; e < 4; ++e)
                qkv[(size_t)(mg + e) * 768 + ng] = f2bf(acc[i][j][e] + bias);
        }
    }
}

// ------------------------------------------------- fused conv + attention ----
// 4x4 pixel tile per block, 256 threads = 1 thread per channel.
// dk weights for this channel (81) live in registers; k/v halo (6x6) in LDS.
__launch_bounds__(256, 2)
__global__ void k_attn(const unsigned short* __restrict__ qkv,
                       const float* __restrict__ dkt,
                       const float* __restrict__ relb,
                       const float* __restrict__ escale,
                       unsigned short* __restrict__ att) {
    __shared__ __align__(16) unsigned short kh[36 * 256];
    __shared__ __align__(16) unsigned short vh[36 * 256];
    __shared__ __align__(16) unsigned short qt[16 * 256];
    const int t = threadIdx.x;
    const int c = t;
    const int head = c >> 5;
    const int w0 = blockIdx.x * 4, h0 = blockIdx.y * 4, b = blockIdx.z;

    float dkr[81];
    #pragma unroll
    for (int l = 0; l < 81; ++l) dkr[l] = dkt[l * 256 + c];
    float rb[9];
    #pragma unroll
    for (int m = 0; m < 9; ++m) rb[m] = relb[head * 9 + m];
    const float es = escale[head];

    // stage k/v halo: 36 pixels x 64 16B-chunks (k: ch 0..31, v: ch 32..63)
    for (int idx = t; idx < 36 * 64; idx += 256) {
        int hp = idx >> 6, ch = idx & 63;
        int hy = h0 - 1 + hp / 6, hx = w0 - 1 + hp % 6;
        i32x4 val = {0, 0, 0, 0};
        if ((unsigned)hy < 64u && (unsigned)hx < 64u)
            val = *(const i32x4*)(qkv + ((size_t)((b * 64 + hy) * 64 + hx)) * 768 + 256 + ch * 8);
        if (ch < 32) *(i32x4*)(kh + hp * 256 + ch * 8) = val;
        else         *(i32x4*)(vh + hp * 256 + (ch - 32) * 8) = val;
    }
    // stage q tile: 16 pixels x 32 chunks
    for (int idx = t; idx < 16 * 32; idx += 256) {
        int p = idx >> 5, ch = idx & 31;
        int iy = h0 + (p >> 2), ix = w0 + (p & 3);
        *(i32x4*)(qt + p * 256 + ch * 8) =
            *(const i32x4*)(qkv + ((size_t)((b * 64 + iy) * 64 + ix)) * 768 + ch * 8);
    }
    __syncthreads();

    for (int p = 0; p < 16; ++p) {
        const int py = p >> 2, px = p & 3;
        const float qv = bf2f(qt[p * 256 + c]);
        float ko[9] = {}, vo[9] = {};
        #pragma unroll
        for (int ij = 0; ij < 9; ++ij) {
            int hp = (py + ij / 3) * 6 + (px + ij % 3);
            float kin = bf2f(kh[hp * 256 + c]);
            float vin = bf2f(vh[hp * 256 + c]);
            #pragma unroll
            for (int m = 0; m < 9; ++m) {
                ko[m] = fmaf(kin, dkr[ij * 9 + m], ko[m]);
                vo[m] = fmaf(vin, dkr[ij * 9 + m], vo[m]);
            }
        }
        // 19 cross-lane (32-wide, within-head) reductions:
        // red[0]=|q|^2, red[1+m]=q.k_m, red[10+m]=|k_m|^2
        float red[19];
        red[0] = qv * qv;
        #pragma unroll
        for (int m = 0; m < 9; ++m) {
            red[1 + m]  = qv * ko[m];
            red[10 + m] = ko[m] * ko[m];
        }
        #pragma unroll
        for (int s = 1; s <= 16; s <<= 1) {
            #pragma unroll
            for (int i = 0; i < 19; ++i) red[i] += __shfl_xor(red[i], s, 64);
        }
        const float rq = rsqrtf(fmaxf(red[0], 1.55e-5f)) * es;
        const int iy = h0 + py, ix = w0 + px;
        float a[9];
        #pragma unroll
        for (int m = 0; m < 9; ++m) {
            float rk = rsqrtf(fmaxf(red[10 + m], 1.55e-5f));
            bool ib = ((unsigned)(iy + m / 3 - 1) < 64u) && ((unsigned)(ix + m % 3 - 1) < 64u);
            a[m] = red[1 + m] * rq * rk + rb[m] + (ib ? 0.f : -100.f);
        }
        float amax = a[0];
        #pragma unroll
        for (int m = 1; m < 9; ++m) amax = fmaxf(amax, a[m]);
        float sum = 0.f, o = 0.f;
        #pragma unroll
        for (int m = 0; m < 9; ++m) { a[m] = __expf(a[m] - amax); sum += a[m]; }
        #pragma unroll
        for (int m = 0; m < 9; ++m) o = fmaf(a[m], vo[m], o);
        o /= sum;
        att[((size_t)((b * 64 + iy) * 64 + ix)) * 256 + c] = f2bf(o);
    }
}

// ------------------------------------------------------------- proj GEMM ----
__launch_bounds__(512, 1)
__global__ void k_proj_gemm(const unsigned short* __restrict__ attin,
                            const unsigned short* __restrict__ pT,
                            const float* __restrict__ pb,
                            float* __restrict__ out) {
    __shared__ __align__(16) unsigned short As[128 * 64];
    __shared__ __align__(16) unsigned short Bs[256 * 64];
    const int t = threadIdx.x;
    const int m0 = blockIdx.x * 128;
    const int wid = t >> 6, lane = t & 63;
    const int wm = wid >> 2, wn = wid & 3;
    const int lr = lane & 15, lk = lane >> 4;
    const int ar = t >> 2, aq = t & 3;
    const int bn = t >> 1, bh = t & 1;
    f32x4 acc[4][4] = {};

    for (int ks = 0; ks < 256; ks += 64) {
        {   // stage A (bf16 rows of att)
            const unsigned short* src = attin + (size_t)(m0 + ar) * 256 + ks + aq * 16;
            s16x8 h0 = *(const s16x8*)(src + 0);
            s16x8 h1 = *(const s16x8*)(src + 8);
            int off = ar * 128 + aq * 32;
            *(s16x8*)((char*)As + swz(off))      = h0;
            *(s16x8*)((char*)As + swz(off + 16)) = h1;
        }
        {   // stage B
            const unsigned short* src = pT + (size_t)bn * 256 + ks + bh * 32;
            s16x8 b0 = *(const s16x8*)(src + 0);
            s16x8 b1 = *(const s16x8*)(src + 8);
            s16x8 b2 = *(const s16x8*)(src + 16);
            s16x8 b3 = *(const s16x8*)(src + 24);
            int off = bn * 128 + bh * 64;
            *(s16x8*)((char*)Bs + swz(off))      = b0;
            *(s16x8*)((char*)Bs + swz(off + 16)) = b1;
            *(s16x8*)((char*)Bs + swz(off + 32)) = b2;
            *(s16x8*)((char*)Bs + swz(off + 48)) = b3;
        }
        __syncthreads();
        #pragma unroll
        for (int kc = 0; kc < 2; ++kc) {
            s16x8 af[4], bfr[4];
            #pragma unroll
            for (int i = 0; i < 4; ++i) {
                int off = (wm * 64 + i * 16 + lr) * 128 + kc * 64 + lk * 16;
                af[i] = *(const s16x8*)((const char*)As + swz(off));
            }
            #pragma unroll
            for (int i = 0; i < 4; ++i) {
                int off = (wn * 64 + i * 16 + lr) * 128 + kc * 64 + lk * 16;
                bfr[i] = *(const s16x8*)((const char*)Bs + swz(off));
            }
            #pragma unroll
            for (int i = 0; i < 4; ++i)
                #pragma unroll
                for (int j = 0; j < 4; ++j)
                    acc[i][j] = __builtin_amdgcn_mfma_f32_16x16x32_bf16(af[i], bfr[j], acc[i][j], 0, 0, 0);
        }
        __syncthreads();
    }
    #pragma unroll
    for (int i = 0; i < 4; ++i) {
        const int mg = m0 + wm * 64 + i * 16 + lk * 4;
        #pragma unroll
        for (int j = 0; j < 4; ++j) {
            const int ng = wn * 64 + j * 16 + lr;
            const float bias = pb[ng];
            #pragma unroll
            for (int e = 0; e < 4; ++e)
                out[(size_t)(mg + e) * 256 + ng] = acc[i][j][e] + bias;
        }
    }
}

// ----------------------------------------------------------------- launch ----
extern "C" void kernel_launch(void* const* d_in, const int* in_sizes, int n_in,
                              void* d_out, int out_size, void* d_ws, size_t ws_size,
                              hipStream_t stream) {
    const float* x  = (const float*)d_in[0];
    const float* wq = (const float*)d_in[1];
    const float* qb = (const float*)d_in[2];
    const float* vb = (const float*)d_in[3];
    const float* dk = (const float*)d_in[4];
    const float* sc = (const float*)d_in[5];
    const float* w1 = (const float*)d_in[6];
    const float* b1 = (const float*)d_in[7];
    const float* w2 = (const float*)d_in[8];
    const float* pw = (const float*)d_in[9];
    const float* pb = (const float*)d_in[10];
    float* out = (float*)d_out;

    char* ws = (char*)d_ws;
    unsigned short* qkv = (unsigned short*)(ws + 0);          // 50,331,648 B
    unsigned short* att = (unsigned short*)(ws + 50331648);   // 16,777,216 B
    float*          dkt = (float*)(ws + 67108864);            //     82,944 B
    unsigned short* wT  = (unsigned short*)(ws + 67191808);   //    393,216 B
    unsigned short* pT  = (unsigned short*)(ws + 67585024);   //    131,072 B
    float*          rlb = (float*)(ws + 67716096);            //        288 B
    float*          esc = (float*)(ws + 67716384);            //         32 B

    hipLaunchKernelGGL(k_setup, dim3(1), dim3(128), 0, stream, sc, w1, b1, w2, rlb, esc);
    hipLaunchKernelGGL(k_transpose, dim3(1105), dim3(256), 0, stream, dk, wq, pw, dkt, wT, pT);
    hipLaunchKernelGGL(k_qkv_gemm, dim3(256, 3), dim3(512), 0, stream, x, wT, qb, vb, qkv);
    hipLaunchKernelGGL(k_attn, dim3(16, 16, 8), dim3(256), 0, stream, qkv, dkt, rlb, esc, att);
    hipLaunchKernelGGL(k_proj_gemm, dim3(256), dim3(512), 0, stream, att, pT, pb, out);
}

// Round 2
// 173.631 us; speedup vs baseline: 1.3164x; 1.3164x over previous
//
#include <hip/hip_runtime.h>
#include <hip/hip_bf16.h>
#include <cstdint>
#include <cstddef>

// SlideAttention fused pipeline for MI355X (gfx950).
// B=8, H=W=64, C=256, HEADS=8, U=32, WIN=3 (9 taps), CPB=512.
//
//  k_setup     : rel_bias[8][9]*log2e via CPB MLP, exp(scale)*log2e
//  k_transpose : dk (3,3,256,9) -> dkh[j][c] packed f16 pairs (l=2j,2j+1);
//                w_qkv -> wT[n][k] bf16 ; proj_w -> pT[n][k] bf16
//  k_qkv_gemm  : qkv[pix][768] bf16 = x @ w_qkv + bias   (MFMA bf16)
//  k_attn      : fused slide-conv (k,v) + cosine attn -> att[pix][256] bf16
//                (f16 weights in VGPRs via v_fma_mix, DPP reductions)
//  k_proj_gemm : out = att @ proj_w + proj_b (f32)       (MFMA bf16)

typedef __attribute__((ext_vector_type(4))) float f32x4;
typedef __attribute__((ext_vector_type(8))) short s16x8;
typedef __attribute__((ext_vector_type(4))) int   i32x4;

#define DEVINL __device__ __forceinline__

DEVINL float bf2f(unsigned short h) {
    unsigned int u = ((unsigned int)h) << 16;
    return __builtin_bit_cast(float, u);
}
DEVINL unsigned short f2bf(float f) {  // RNE, finite inputs only
    unsigned int u = __builtin_bit_cast(unsigned int, f);
    u += 0x7FFFu + ((u >> 16) & 1u);
    return (unsigned short)(u >> 16);
}
// LDS xor-swizzle for GEMM tiles (rows 128 B)
DEVINL int swz(int off) { return off ^ ((off >> 3) & 0x70); }

// ---------------------------------------------------------------- setup ----
__global__ void k_setup(const float* __restrict__ scale,
                        const float* __restrict__ w1,
                        const float* __restrict__ b1,
                        const float* __restrict__ w2,
                        float* __restrict__ relb,
                        float* __restrict__ escale) {
    const float LOG2E = 1.4426950408889634f;
    int t = threadIdx.x;
    if (t < 72) {
        int m = t / 8, head = t % 8;
        float dy = (float)(m / 3 - 1), dx = (float)(m % 3 - 1);
        const float il8 = 0.48089834696298783f; // 1/ln(8)
        float r0 = (dy > 0.f ? 1.f : (dy < 0.f ? -1.f : 0.f)) * log1pf(fabsf(dy)) * il8;
        float r1 = (dx > 0.f ? 1.f : (dx < 0.f ? -1.f : 0.f)) * log1pf(fabsf(dx)) * il8;
        float acc = 0.f;
        for (int j = 0; j < 512; ++j) {
            float h = fmaxf(r0 * w1[j] + r1 * w1[512 + j] + b1[j], 0.f);
            acc += h * w2[j * 8 + head];
        }
        relb[head * 9 + m] = 16.f / (1.f + expf(-acc)) * LOG2E;  // log2-domain
    } else if (t < 80) {
        escale[t - 72] = expf(scale[t - 72]) * LOG2E;            // log2-domain
    }
}

// ------------------------------------------------------------ transpose ----
__global__ void k_transpose(const float* __restrict__ dk,
                            const float* __restrict__ wq,
                            const float* __restrict__ pw,
                            unsigned int* __restrict__ dkh,
                            unsigned short* __restrict__ wT,
                            unsigned short* __restrict__ pT) {
    int i = blockIdx.x * blockDim.x + threadIdx.x;
    if (i < 10496) {       // dkh[j*256+c] = f16(dk[l=2j][c]) | f16(dk[l=2j+1][c])<<16
        int j = i >> 8, c = i & 255;
        int l0 = 2 * j, l1 = 2 * j + 1;
        float f0 = dk[((l0 / 9) * 256 + c) * 9 + (l0 % 9)];
        float f1 = (l1 < 81) ? dk[((l1 / 9) * 256 + c) * 9 + (l1 % 9)] : 0.f;
        unsigned short h0 = __builtin_bit_cast(unsigned short, (_Float16)f0);
        unsigned short h1 = __builtin_bit_cast(unsigned short, (_Float16)f1);
        dkh[i] = (unsigned int)h0 | ((unsigned int)h1 << 16);
        return;
    }
    int j = i - 10496;
    if (j < 196608) {                   // wT[n*256+k] = bf16(wq[k*768+n])
        int n = j >> 8, k = j & 255;
        wT[j] = f2bf(wq[k * 768 + n]);
        return;
    }
    int p = j - 196608;
    if (p < 65536) {                    // pT[n*256+k] = bf16(pw[k*256+n])
        int n = p >> 8, k = p & 255;
        pT[p] = f2bf(pw[k * 256 + n]);
    }
}

// ------------------------------------------------------------- qkv GEMM ----
__launch_bounds__(512, 1)
__global__ void k_qkv_gemm(const float* __restrict__ x,
                           const unsigned short* __restrict__ wT,
                           const float* __restrict__ qb,
                           const float* __restrict__ vb,
                           unsigned short* __restrict__ qkv) {
    __shared__ __align__(16) unsigned short As[128 * 64];
    __shared__ __align__(16) unsigned short Bs[256 * 64];
    const int t = threadIdx.x;
    const int m0 = blockIdx.x * 128;
    const int n0 = blockIdx.y * 256;
    const int wid = t >> 6, lane = t & 63;
    const int wm = wid >> 2, wn = wid & 3;
    const int lr = lane & 15, lk = lane >> 4;
    const int ar = t >> 2, aq = t & 3;
    const int bn = t >> 1, bh = t & 1;
    f32x4 acc[4][4] = {};

    for (int ks = 0; ks < 256; ks += 64) {
        {   // stage A (f32 -> bf16)
            const float* src = x + (size_t)(m0 + ar) * 256 + ks + aq * 16;
            f32x4 v0 = *(const f32x4*)(src + 0);
            f32x4 v1 = *(const f32x4*)(src + 4);
            f32x4 v2 = *(const f32x4*)(src + 8);
            f32x4 v3 = *(const f32x4*)(src + 12);
            s16x8 h0, h1;
            h0[0]=(short)f2bf(v0[0]); h0[1]=(short)f2bf(v0[1]); h0[2]=(short)f2bf(v0[2]); h0[3]=(short)f2bf(v0[3]);
            h0[4]=(short)f2bf(v1[0]); h0[5]=(short)f2bf(v1[1]); h0[6]=(short)f2bf(v1[2]); h0[7]=(short)f2bf(v1[3]);
            h1[0]=(short)f2bf(v2[0]); h1[1]=(short)f2bf(v2[1]); h1[2]=(short)f2bf(v2[2]); h1[3]=(short)f2bf(v2[3]);
            h1[4]=(short)f2bf(v3[0]); h1[5]=(short)f2bf(v3[1]); h1[6]=(short)f2bf(v3[2]); h1[7]=(short)f2bf(v3[3]);
            int off = ar * 128 + aq * 32;
            *(s16x8*)((char*)As + swz(off))      = h0;
            *(s16x8*)((char*)As + swz(off + 16)) = h1;
        }
        {   // stage B (already bf16, K-major)
            const unsigned short* src = wT + (size_t)(n0 + bn) * 256 + ks + bh * 32;
            s16x8 b0 = *(const s16x8*)(src + 0);
            s16x8 b1 = *(const s16x8*)(src + 8);
            s16x8 b2 = *(const s16x8*)(src + 16);
            s16x8 b3 = *(const s16x8*)(src + 24);
            int off = bn * 128 + bh * 64;
            *(s16x8*)((char*)Bs + swz(off))      = b0;
            *(s16x8*)((char*)Bs + swz(off + 16)) = b1;
            *(s16x8*)((char*)Bs + swz(off + 32)) = b2;
            *(s16x8*)((char*)Bs + swz(off + 48)) = b3;
        }
        __syncthreads();
        #pragma unroll
        for (int kc = 0; kc < 2; ++kc) {
            s16x8 af[4], bfr[4];
            #pragma unroll
            for (int i = 0; i < 4; ++i) {
                int off = (wm * 64 + i * 16 + lr) * 128 + kc * 64 + lk * 16;
                af[i] = *(const s16x8*)((const char*)As + swz(off));
            }
            #pragma unroll
            for (int i = 0; i < 4; ++i) {
                int off = (wn * 64 + i * 16 + lr) * 128 + kc * 64 + lk * 16;
                bfr[i] = *(const s16x8*)((const char*)Bs + swz(off));
            }
            #pragma unroll
            for (int i = 0; i < 4; ++i)
                #pragma unroll
                for (int j = 0; j < 4; ++j)
                    acc[i][j] = __builtin_amdgcn_mfma_f32_16x16x32_bf16(af[i], bfr[j], acc[i][j], 0, 0, 0);
        }
        __syncthreads();
    }
    #pragma unroll
    for (int i = 0; i < 4; ++i) {
        const int mg = m0 + wm * 64 + i * 16 + lk * 4;
        #pragma unroll
        for (int j = 0; j < 4; ++j) {
            const int ng = n0 + wn * 64 + j * 16 + lr;
            float bias = (ng < 256) ? qb[ng] : ((ng < 512) ? 0.f : vb[ng - 512]);
            #pragma unroll
            for (int e = 0; e < 4; ++e)
                qkv[(size_t)(mg + e) * 768 + ng] = f2bf(acc[i][j][e] + bias);
        }
    }
}

// ------------------------------------------------- fused conv + attention ----
// 4x4 pixel tile, 256 threads = 1 thread/channel.
// dk weights: 41 packed-f16 VGPRs consumed via v_fma_mix.
// k/v halo interleaved (one u32/channel) in LDS (36.9 KB -> 4 blocks/CU).
// 32-lane reductions: 4x DPP-fused adds + 1 ds_swizzle(xor16).

template <int CTRL>
DEVINL float dpp_add(float x) {
    int r = __builtin_amdgcn_update_dpp(0, __builtin_bit_cast(int, x),
                                        CTRL, 0xF, 0xF, true);
    return x + __builtin_bit_cast(float, r);
}
DEVINL float red32(float x) {
    x = dpp_add<0xB1>(x);   // quad_perm [1,0,3,2]  : xor1
    x = dpp_add<0x4E>(x);   // quad_perm [2,3,0,1]  : xor2
    x = dpp_add<0x141>(x);  // row_half_mirror      : xor within 8
    x = dpp_add<0x140>(x);  // row_mirror           : xor within 16
    int s = __builtin_amdgcn_ds_swizzle(__builtin_bit_cast(int, x), 0x401F); // xor16
    return x + __builtin_bit_cast(float, s);
}
DEVINL float wgt(const unsigned int* wp, int l) {  // static l
    unsigned int u = wp[l >> 1];
    unsigned short h = (l & 1) ? (unsigned short)(u >> 16) : (unsigned short)(u & 0xFFFF);
    return (float)__builtin_bit_cast(_Float16, h);
}

__launch_bounds__(256, 4)
__global__ void k_attn(const unsigned short* __restrict__ qkv,
                       const unsigned int* __restrict__ dkh,
                       const float* __restrict__ relb,
                       const float* __restrict__ escale,
                       unsigned short* __restrict__ att) {
    __shared__ __align__(16) unsigned int kv[36 * 256];   // (k | v<<16) bf16 pair
    const int t = threadIdx.x;
    const int c = t;
    const int head = c >> 5;
    const int w0 = blockIdx.x * 4, h0 = blockIdx.y * 4, b = blockIdx.z;

    unsigned int wp[41];
    #pragma unroll
    for (int j = 0; j < 41; ++j) wp[j] = dkh[j * 256 + c];
    float rb[9];
    #pragma unroll
    for (int m = 0; m < 9; ++m) rb[m] = relb[head * 9 + m];
    const float es2 = escale[head];          // exp(scale)*log2e

    // stage k/v halo, interleaved: 36 px x 32 8-channel groups
    for (int idx = t; idx < 36 * 32; idx += 256) {
        int hp = idx >> 5, ch = idx & 31;
        int hy = h0 - 1 + hp / 6, hx = w0 - 1 + hp % 6;
        i32x4 kk = {0, 0, 0, 0}, vv = {0, 0, 0, 0};
        if ((unsigned)hy < 64u && (unsigned)hx < 64u) {
            const unsigned short* base = qkv + ((size_t)((b * 64 + hy) * 64 + hx)) * 768;
            kk = *(const i32x4*)(base + 256 + ch * 8);
            vv = *(const i32x4*)(base + 512 + ch * 8);
        }
        i32x4 p0, p1;
        #pragma unroll
        for (int e = 0; e < 4; ++e) {
            unsigned int k2 = (unsigned int)kk[e], v2 = (unsigned int)vv[e];
            unsigned int lo = (k2 & 0xFFFFu) | (v2 << 16);
            unsigned int hi = (k2 >> 16)     | (v2 & 0xFFFF0000u);
            if (e < 2) { p0[2 * e] = (int)lo; p0[2 * e + 1] = (int)hi; }
            else       { p1[2 * (e - 2)] = (int)lo; p1[2 * (e - 2) + 1] = (int)hi; }
        }
        *(i32x4*)(kv + hp * 256 + ch * 8)     = p0;
        *(i32x4*)(kv + hp * 256 + ch * 8 + 4) = p1;
    }
    __syncthreads();

    for (int p = 0; p < 16; ++p) {
        const int py = p >> 2, px = p & 3;
        const int iy = h0 + py, ix = w0 + px;
        const float qv = bf2f(qkv[((size_t)((b * 64 + iy) * 64 + ix)) * 768 + c]);

        float kin[9], vin[9];
        #pragma unroll
        for (int ij = 0; ij < 9; ++ij) {
            unsigned int u = kv[((py + ij / 3) * 6 + (px + ij % 3)) * 256 + c];
            kin[ij] = __builtin_bit_cast(float, u << 16);
            vin[ij] = __builtin_bit_cast(float, u & 0xFFFF0000u);
        }
        float ko[9], vo[9];
        #pragma unroll
        for (int m = 0; m < 9; ++m) { ko[m] = kin[m]; vo[m] = vin[m]; }  // identity tap
        #pragma unroll
        for (int ij = 0; ij < 9; ++ij)
            #pragma unroll
            for (int m = 0; m < 9; ++m)
                if (ij != m) {
                    float w = wgt(wp, ij * 9 + m);   // -> v_fma_mix_f32
                    ko[m] = fmaf(kin[ij], w, ko[m]);
                    vo[m] = fmaf(vin[ij], w, vo[m]);
                }

        float red[19];
        red[0] = qv * qv;
        #pragma unroll
        for (int m = 0; m < 9; ++m) {
            red[1 + m]  = qv * ko[m];
            red[10 + m] = ko[m] * ko[m];
        }
        #pragma unroll
        for (int i = 0; i < 19; ++i) red[i] = red32(red[i]);

        const float rq = __builtin_amdgcn_rsqf(fmaxf(red[0], 1.55e-5f)) * es2;
        const bool yt = (iy == 0), yb = (iy == 63), xl = (ix == 0), xr = (ix == 63);
        const float NEG = -144.2695040888963f;  // -100*log2e
        float a[9];
        #pragma unroll
        for (int m = 0; m < 9; ++m) {
            float rk = __builtin_amdgcn_rsqf(fmaxf(red[10 + m], 1.55e-5f));
            int dy = m / 3 - 1, dx = m % 3 - 1;
            bool oob = (dy < 0 && yt) || (dy > 0 && yb) || (dx < 0 && xl) || (dx > 0 && xr);
            a[m] = red[1 + m] * rq * rk + rb[m] + (oob ? NEG : 0.f);
        }
        float amax = a[0];
        #pragma unroll
        for (int m = 1; m < 9; ++m) amax = fmaxf(amax, a[m]);
        float sum = 0.f, o = 0.f;
        #pragma unroll
        for (int m = 0; m < 9; ++m) {
            float e = exp2f(a[m] - amax);
            sum += e;
            o = fmaf(e, vo[m], o);
        }
        o *= __builtin_amdgcn_rcpf(sum);
        att[((size_t)((b * 64 + iy) * 64 + ix)) * 256 + c] = f2bf(o);
    }
}

// ------------------------------------------------------------- proj GEMM ----
__launch_bounds__(512, 1)
__global__ void k_proj_gemm(const unsigned short* __restrict__ attin,
                            const unsigned short* __restrict__ pT,
                            const float* __restrict__ pb,
                            float* __restrict__ out) {
    __shared__ __align__(16) unsigned short As[128 * 64];
    __shared__ __align__(16) unsigned short Bs[256 * 64];
    const int t = threadIdx.x;
    const int m0 = blockIdx.x * 128;
    const int wid = t >> 6, lane = t & 63;
    const int wm = wid >> 2, wn = wid & 3;
    const int lr = lane & 15, lk = lane >> 4;
    const int ar = t >> 2, aq = t & 3;
    const int bn = t >> 1, bh = t & 1;
    f32x4 acc[4][4] = {};

    for (int ks = 0; ks < 256; ks += 64) {
        {   // stage A (bf16 rows of att)
            const unsigned short* src = attin + (size_t)(m0 + ar) * 256 + ks + aq * 16;
            s16x8 h0 = *(const s16x8*)(src + 0);
            s16x8 h1 = *(const s16x8*)(src + 8);
            int off = ar * 128 + aq * 32;
            *(s16x8*)((char*)As + swz(off))      = h0;
            *(s16x8*)((char*)As + swz(off + 16)) = h1;
        }
        {   // stage B
            const unsigned short* src = pT + (size_t)bn * 256 + ks + bh * 32;
            s16x8 b0 = *(const s16x8*)(src + 0);
            s16x8 b1 = *(const s16x8*)(src + 8);
            s16x8 b2 = *(const s16x8*)(src + 16);
            s16x8 b3 = *(const s16x8*)(src + 24);
            int off = bn * 128 + bh * 64;
            *(s16x8*)((char*)Bs + swz(off))      = b0;
            *(s16x8*)((char*)Bs + swz(off + 16)) = b1;
            *(s16x8*)((char*)Bs + swz(off + 32)) = b2;
            *(s16x8*)((char*)Bs + swz(off + 48)) = b3;
        }
        __syncthreads();
        #pragma unroll
        for (int kc = 0; kc < 2; ++kc) {
            s16x8 af[4], bfr[4];
            #pragma unroll
            for (int i = 0; i < 4; ++i) {
                int off = (wm * 64 + i * 16 + lr) * 128 + kc * 64 + lk * 16;
                af[i] = *(const s16x8*)((const char*)As + swz(off));
            }
            #pragma unroll
            for (int i = 0; i < 4; ++i) {
                int off = (wn * 64 + i * 16 + lr) * 128 + kc * 64 + lk * 16;
                bfr[i] = *(const s16x8*)((const char*)Bs + swz(off));
            }
            #pragma unroll
            for (int i = 0; i < 4; ++i)
                #pragma unroll
                for (int j = 0; j < 4; ++j)
                    acc[i][j] = __builtin_amdgcn_mfma_f32_16x16x32_bf16(af[i], bfr[j], acc[i][j], 0, 0, 0);
        }
        __syncthreads();
    }
    #pragma unroll
    for (int i = 0; i < 4; ++i) {
        const int mg = m0 + wm * 64 + i * 16 + lk * 4;
        #pragma unroll
        for (int j = 0; j < 4; ++j) {
            const int ng = wn * 64 + j * 16 + lr;
            const float bias = pb[ng];
            #pragma unroll
            for (int e = 0; e < 4; ++e)
                out[(size_t)(mg + e) * 256 + ng] = acc[i][j][e] + bias;
        }
    }
}

// ----------------------------------------------------------------- launch ----
extern "C" void kernel_launch(void* const* d_in, const int* in_sizes, int n_in,
                              void* d_out, int out_size, void* d_ws, size_t ws_size,
                              hipStream_t stream) {
    const float* x  = (const float*)d_in[0];
    const float* wq = (const float*)d_in[1];
    const float* qb = (const float*)d_in[2];
    const float* vb = (const float*)d_in[3];
    const float* dk = (const float*)d_in[4];
    const float* sc = (const float*)d_in[5];
    const float* w1 = (const float*)d_in[6];
    const float* b1 = (const float*)d_in[7];
    const float* w2 = (const float*)d_in[8];
    const float* pw = (const float*)d_in[9];
    const float* pb = (const float*)d_in[10];
    float* out = (float*)d_out;

    char* ws = (char*)d_ws;
    unsigned short* qkv = (unsigned short*)(ws + 0);          // 50,331,648 B
    unsigned short* att = (unsigned short*)(ws + 50331648);   // 16,777,216 B
    unsigned int*   dkh = (unsigned int*)(ws + 67108864);     //     41,984 B
    unsigned short* wT  = (unsigned short*)(ws + 67150848);   //    393,216 B
    unsigned short* pT  = (unsigned short*)(ws + 67544064);   //    131,072 B
    float*          rlb = (float*)(ws + 67675136);            //        288 B
    float*          esc = (float*)(ws + 67675424);            //         32 B

    hipLaunchKernelGGL(k_setup, dim3(1), dim3(128), 0, stream, sc, w1, b1, w2, rlb, esc);
    hipLaunchKernelGGL(k_transpose, dim3(1065), dim3(256), 0, stream, dk, wq, pw, dkh, wT, pT);
    hipLaunchKernelGGL(k_qkv_gemm, dim3(256, 3), dim3(512), 0, stream, x, wT, qb, vb, qkv);
    hipLaunchKernelGGL(k_attn, dim3(16, 16, 8), dim3(256), 0, stream, qkv, dkh, rlb, esc, att);
    hipLaunchKernelGGL(k_proj_gemm, dim3(256), dim3(512), 0, stream, att, pT, pb, out);
}

// Round 3
// 171.417 us; speedup vs baseline: 1.3334x; 1.0129x over previous
//
#include <hip/hip_runtime.h>
#include <hip/hip_bf16.h>
#include <cstdint>
#include <cstddef>

// SlideAttention fused pipeline for MI355X (gfx950).
// B=8, H=W=64, C=256, HEADS=8, U=32, WIN=3 (9 taps), CPB=512.
//
//  k_setup     : rel_bias[8][9]*log2e via CPB MLP, exp(scale)*log2e
//  k_transpose : dk (3,3,256,9) -> dkh[j][c] packed f16 pairs (l=2j,2j+1);
//                w_qkv -> wT[n][k] bf16 ; proj_w -> pT[n][k] bf16
//  k_qkv_gemm  : qkv[pix][768] f16 = x @ w_qkv + bias   (MFMA bf16)
//  k_attn      : fused slide-conv (k,v) + cosine attn -> att[pix][256] bf16
//                (all conv MACs as v_fma_mix via <2 x half> extracts)
//  k_proj_gemm : out = att @ proj_w + proj_b (f32)       (MFMA bf16)

typedef __attribute__((ext_vector_type(4))) float f32x4;
typedef __attribute__((ext_vector_type(8))) short s16x8;
typedef __attribute__((ext_vector_type(4))) int   i32x4;
typedef _Float16 h2 __attribute__((ext_vector_type(2)));

#define DEVINL __device__ __forceinline__

DEVINL float bf2f(unsigned short h) {
    unsigned int u = ((unsigned int)h) << 16;
    return __builtin_bit_cast(float, u);
}
DEVINL unsigned short f2bf(float f) {  // RNE, finite inputs only
    unsigned int u = __builtin_bit_cast(unsigned int, f);
    u += 0x7FFFu + ((u >> 16) & 1u);
    return (unsigned short)(u >> 16);
}
// LDS xor-swizzle for GEMM tiles (rows 128 B)
DEVINL int swz(int off) { return off ^ ((off >> 3) & 0x70); }

DEVINL float fexp2(float x) {
#if __has_builtin(__builtin_amdgcn_exp2f)
    return __builtin_amdgcn_exp2f(x);
#else
    return exp2f(x);
#endif
}

// ---------------------------------------------------------------- setup ----
__global__ void k_setup(const float* __restrict__ scale,
                        const float* __restrict__ w1,
                        const float* __restrict__ b1,
                        const float* __restrict__ w2,
                        float* __restrict__ relb,
                        float* __restrict__ escale) {
    const float LOG2E = 1.4426950408889634f;
    int t = threadIdx.x;
    if (t < 72) {
        int m = t / 8, head = t % 8;
        float dy = (float)(m / 3 - 1), dx = (float)(m % 3 - 1);
        const float il8 = 0.48089834696298783f; // 1/ln(8)
        float r0 = (dy > 0.f ? 1.f : (dy < 0.f ? -1.f : 0.f)) * log1pf(fabsf(dy)) * il8;
        float r1 = (dx > 0.f ? 1.f : (dx < 0.f ? -1.f : 0.f)) * log1pf(fabsf(dx)) * il8;
        float acc = 0.f;
        for (int j = 0; j < 512; ++j) {
            float h = fmaxf(r0 * w1[j] + r1 * w1[512 + j] + b1[j], 0.f);
            acc += h * w2[j * 8 + head];
        }
        relb[head * 9 + m] = 16.f / (1.f + expf(-acc)) * LOG2E;  // log2-domain
    } else if (t < 80) {
        escale[t - 72] = expf(scale[t - 72]) * LOG2E;            // log2-domain
    }
}

// ------------------------------------------------------------ transpose ----
__global__ void k_transpose(const float* __restrict__ dk,
                            const float* __restrict__ wq,
                            const float* __restrict__ pw,
                            unsigned int* __restrict__ dkh,
                            unsigned short* __restrict__ wT,
                            unsigned short* __restrict__ pT) {
    int i = blockIdx.x * blockDim.x + threadIdx.x;
    if (i < 10496) {       // dkh[j*256+c] = f16(dk[l=2j][c]) | f16(dk[l=2j+1][c])<<16
        int j = i >> 8, c = i & 255;
        int l0 = 2 * j, l1 = 2 * j + 1;
        float f0 = dk[((l0 / 9) * 256 + c) * 9 + (l0 % 9)];
        float f1 = (l1 < 81) ? dk[((l1 / 9) * 256 + c) * 9 + (l1 % 9)] : 0.f;
        unsigned short h0 = __builtin_bit_cast(unsigned short, (_Float16)f0);
        unsigned short h1 = __builtin_bit_cast(unsigned short, (_Float16)f1);
        dkh[i] = (unsigned int)h0 | ((unsigned int)h1 << 16);
        return;
    }
    int j = i - 10496;
    if (j < 196608) {                   // wT[n*256+k] = bf16(wq[k*768+n])
        int n = j >> 8, k = j & 255;
        wT[j] = f2bf(wq[k * 768 + n]);
        return;
    }
    int p = j - 196608;
    if (p < 65536) {                    // pT[n*256+k] = bf16(pw[k*256+n])
        int n = p >> 8, k = p & 255;
        pT[p] = f2bf(pw[k * 256 + n]);
    }
}

// ------------------------------------------------------------- qkv GEMM ----
__launch_bounds__(512, 1)
__global__ void k_qkv_gemm(const float* __restrict__ x,
                           const unsigned short* __restrict__ wT,
                           const float* __restrict__ qb,
                           const float* __restrict__ vb,
                           unsigned short* __restrict__ qkv) {
    __shared__ __align__(16) unsigned short As[128 * 64];
    __shared__ __align__(16) unsigned short Bs[256 * 64];
    const int t = threadIdx.x;
    const int m0 = blockIdx.x * 128;
    const int n0 = blockIdx.y * 256;
    const int wid = t >> 6, lane = t & 63;
    const int wm = wid >> 2, wn = wid & 3;
    const int lr = lane & 15, lk = lane >> 4;
    const int ar = t >> 2, aq = t & 3;
    const int bn = t >> 1, bh = t & 1;
    f32x4 acc[4][4] = {};

    for (int ks = 0; ks < 256; ks += 64) {
        {   // stage A (f32 -> bf16)
            const float* src = x + (size_t)(m0 + ar) * 256 + ks + aq * 16;
            f32x4 v0 = *(const f32x4*)(src + 0);
            f32x4 v1 = *(const f32x4*)(src + 4);
            f32x4 v2 = *(const f32x4*)(src + 8);
            f32x4 v3 = *(const f32x4*)(src + 12);
            s16x8 h0, h1;
            h0[0]=(short)f2bf(v0[0]); h0[1]=(short)f2bf(v0[1]); h0[2]=(short)f2bf(v0[2]); h0[3]=(short)f2bf(v0[3]);
            h0[4]=(short)f2bf(v1[0]); h0[5]=(short)f2bf(v1[1]); h0[6]=(short)f2bf(v1[2]); h0[7]=(short)f2bf(v1[3]);
            h1[0]=(short)f2bf(v2[0]); h1[1]=(short)f2bf(v2[1]); h1[2]=(short)f2bf(v2[2]); h1[3]=(short)f2bf(v2[3]);
            h1[4]=(short)f2bf(v3[0]); h1[5]=(short)f2bf(v3[1]); h1[6]=(short)f2bf(v3[2]); h1[7]=(short)f2bf(v3[3]);
            int off = ar * 128 + aq * 32;
            *(s16x8*)((char*)As + swz(off))      = h0;
            *(s16x8*)((char*)As + swz(off + 16)) = h1;
        }
        {   // stage B (already bf16, K-major)
            const unsigned short* src = wT + (size_t)(n0 + bn) * 256 + ks + bh * 32;
            s16x8 b0 = *(const s16x8*)(src + 0);
            s16x8 b1 = *(const s16x8*)(src + 8);
            s16x8 b2 = *(const s16x8*)(src + 16);
            s16x8 b3 = *(const s16x8*)(src + 24);
            int off = bn * 128 + bh * 64;
            *(s16x8*)((char*)Bs + swz(off))      = b0;
            *(s16x8*)((char*)Bs + swz(off + 16)) = b1;
            *(s16x8*)((char*)Bs + swz(off + 32)) = b2;
            *(s16x8*)((char*)Bs + swz(off + 48)) = b3;
        }
        __syncthreads();
        #pragma unroll
        for (int kc = 0; kc < 2; ++kc) {
            s16x8 af[4], bfr[4];
            #pragma unroll
            for (int i = 0; i < 4; ++i) {
                int off = (wm * 64 + i * 16 + lr) * 128 + kc * 64 + lk * 16;
                af[i] = *(const s16x8*)((const char*)As + swz(off));
            }
            #pragma unroll
            for (int i = 0; i < 4; ++i) {
                int off = (wn * 64 + i * 16 + lr) * 128 + kc * 64 + lk * 16;
                bfr[i] = *(const s16x8*)((const char*)Bs + swz(off));
            }
            #pragma unroll
            for (int i = 0; i < 4; ++i)
                #pragma unroll
                for (int j = 0; j < 4; ++j)
                    acc[i][j] = __builtin_amdgcn_mfma_f32_16x16x32_bf16(af[i], bfr[j], acc[i][j], 0, 0, 0);
        }
        __syncthreads();
    }
    #pragma unroll
    for (int i = 0; i < 4; ++i) {
        const int mg = m0 + wm * 64 + i * 16 + lk * 4;
        #pragma unroll
        for (int j = 0; j < 4; ++j) {
            const int ng = n0 + wn * 64 + j * 16 + lr;
            float bias = (ng < 256) ? qb[ng] : ((ng < 512) ? 0.f : vb[ng - 512]);
            #pragma unroll
            for (int e = 0; e < 4; ++e)
                qkv[(size_t)(mg + e) * 768 + ng] =
                    __builtin_bit_cast(unsigned short, (_Float16)(acc[i][j][e] + bias));
        }
    }
}

// ------------------------------------------------- fused conv + attention ----
// 4x4 pixel tile, 256 threads = 1 thread/channel.
// qkv is f16; LDS holds (k|v) f16-packed per channel (one u32).
// Conv MACs: v_fma_mix_f32 via native <2 x half> element extracts (op_sel).
// 32-lane reductions: 4x DPP-fused adds + 1 ds_swizzle(xor16).

template <int CTRL>
DEVINL float dpp_add(float x) {
    int r = __builtin_amdgcn_update_dpp(0, __builtin_bit_cast(int, x),
                                        CTRL, 0xF, 0xF, true);
    return x + __builtin_bit_cast(float, r);
}
DEVINL float red32(float x) {
    x = dpp_add<0xB1>(x);   // quad_perm [1,0,3,2]  : xor1
    x = dpp_add<0x4E>(x);   // quad_perm [2,3,0,1]  : xor2
    x = dpp_add<0x141>(x);  // row_half_mirror      : xor within 8
    x = dpp_add<0x140>(x);  // row_mirror           : xor within 16
    int s = __builtin_amdgcn_ds_swizzle(__builtin_bit_cast(int, x), 0x401F); // xor16
    return x + __builtin_bit_cast(float, s);
}

__launch_bounds__(256, 2)
__global__ void k_attn(const unsigned short* __restrict__ qkv,
                       const unsigned int* __restrict__ dkh,
                       const float* __restrict__ relb,
                       const float* __restrict__ escale,
                       unsigned short* __restrict__ att) {
    __shared__ __align__(16) unsigned int kv[36 * 256];   // (k | v<<16) f16 pair
    const int t = threadIdx.x;
    const int c = t;
    const int head = c >> 5;
    const int w0 = blockIdx.x * 4, h0 = blockIdx.y * 4, b = blockIdx.z;

    h2 wv[41];
    #pragma unroll
    for (int j = 0; j < 41; ++j) wv[j] = __builtin_bit_cast(h2, dkh[j * 256 + c]);
    float rb[9];
    #pragma unroll
    for (int m = 0; m < 9; ++m) rb[m] = relb[head * 9 + m];
    const float es2 = escale[head];          // exp(scale)*log2e

    // stage k/v halo, interleaved via v_perm: 36 px x 32 8-channel groups
    for (int idx = t; idx < 36 * 32; idx += 256) {
        int hp = idx >> 5, ch = idx & 31;
        int hy = h0 - 1 + hp / 6, hx = w0 - 1 + hp % 6;
        i32x4 kk = {0, 0, 0, 0}, vv = {0, 0, 0, 0};
        if ((unsigned)hy < 64u && (unsigned)hx < 64u) {
            const unsigned short* base = qkv + ((size_t)((b * 64 + hy) * 64 + hx)) * 768;
            kk = *(const i32x4*)(base + 256 + ch * 8);
            vv = *(const i32x4*)(base + 512 + ch * 8);
        }
        i32x4 p0, p1;
        #pragma unroll
        for (int e = 0; e < 4; ++e) {
            unsigned lo = __builtin_amdgcn_perm((unsigned)vv[e], (unsigned)kk[e], 0x05040100u);
            unsigned hi = __builtin_amdgcn_perm((unsigned)vv[e], (unsigned)kk[e], 0x07060302u);
            if (e < 2) { p0[2 * e] = (int)lo; p0[2 * e + 1] = (int)hi; }
            else       { p1[2 * (e - 2)] = (int)lo; p1[2 * (e - 2) + 1] = (int)hi; }
        }
        *(i32x4*)(kv + hp * 256 + ch * 8)     = p0;
        *(i32x4*)(kv + hp * 256 + ch * 8 + 4) = p1;
    }
    __syncthreads();

    for (int p = 0; p < 16; ++p) {
        const int py = p >> 2, px = p & 3;
        const int iy = h0 + py, ix = w0 + px;
        const float qv = (float)__builtin_bit_cast(_Float16,
            qkv[((size_t)((b * 64 + iy) * 64 + ix)) * 768 + c]);

        h2 kvp[9];
        #pragma unroll
        for (int ij = 0; ij < 9; ++ij)
            kvp[ij] = __builtin_bit_cast(h2,
                kv[((py + ij / 3) * 6 + (px + ij % 3)) * 256 + c]);

        float ko[9], vo[9];
        #pragma unroll
        for (int m = 0; m < 9; ++m) {      // identity tap (weight == 1.0)
            ko[m] = (float)kvp[m].x;
            vo[m] = (float)kvp[m].y;
        }
        #pragma unroll
        for (int ij = 0; ij < 9; ++ij)
            #pragma unroll
            for (int m = 0; m < 9; ++m)
                if (ij != m) {
                    const int l = ij * 9 + m;
                    if (l & 1) {
                        ko[m] = fmaf((float)kvp[ij].x, (float)wv[l >> 1].y, ko[m]);
                        vo[m] = fmaf((float)kvp[ij].y, (float)wv[l >> 1].y, vo[m]);
                    } else {
                        ko[m] = fmaf((float)kvp[ij].x, (float)wv[l >> 1].x, ko[m]);
                        vo[m] = fmaf((float)kvp[ij].y, (float)wv[l >> 1].x, vo[m]);
                    }
                }

        float red[19];
        red[0] = qv * qv;
        #pragma unroll
        for (int m = 0; m < 9; ++m) {
            red[1 + m]  = qv * ko[m];
            red[10 + m] = ko[m] * ko[m];
        }
        #pragma unroll
        for (int i = 0; i < 19; ++i) red[i] = red32(red[i]);

        const float rq = __builtin_amdgcn_rsqf(fmaxf(red[0], 1.55e-5f)) * es2;
        const bool yt = (iy == 0), yb = (iy == 63), xl = (ix == 0), xr = (ix == 63);
        const float NEG = -144.2695040888963f;  // -100*log2e
        float a[9];
        #pragma unroll
        for (int m = 0; m < 9; ++m) {
            float rk = __builtin_amdgcn_rsqf(fmaxf(red[10 + m], 1.55e-5f));
            int dy = m / 3 - 1, dx = m % 3 - 1;
            bool oob = (dy < 0 && yt) || (dy > 0 && yb) || (dx < 0 && xl) || (dx > 0 && xr);
            a[m] = red[1 + m] * rq * rk + rb[m] + (oob ? NEG : 0.f);
        }
        float sum = 0.f, o = 0.f;   // no max-subtract: a in [-182, 38], exp2 safe
        #pragma unroll
        for (int m = 0; m < 9; ++m) {
            float e = fexp2(a[m]);
            sum += e;
            o = fmaf(e, vo[m], o);
        }
        o *= __builtin_amdgcn_rcpf(sum);
        att[((size_t)((b * 64 + iy) * 64 + ix)) * 256 + c] = f2bf(o);
    }
}

// ------------------------------------------------------------- proj GEMM ----
__launch_bounds__(512, 1)
__global__ void k_proj_gemm(const unsigned short* __restrict__ attin,
                            const unsigned short* __restrict__ pT,
                            const float* __restrict__ pb,
                            float* __restrict__ out) {
    __shared__ __align__(16) unsigned short As[128 * 64];
    __shared__ __align__(16) unsigned short Bs[256 * 64];
    const int t = threadIdx.x;
    const int m0 = blockIdx.x * 128;
    const int wid = t >> 6, lane = t & 63;
    const int wm = wid >> 2, wn = wid & 3;
    const int lr = lane & 15, lk = lane >> 4;
    const int ar = t >> 2, aq = t & 3;
    const int bn = t >> 1, bh = t & 1;
    f32x4 acc[4][4] = {};

    for (int ks = 0; ks < 256; ks += 64) {
        {   // stage A (bf16 rows of att)
            const unsigned short* src = attin + (size_t)(m0 + ar) * 256 + ks + aq * 16;
            s16x8 h0 = *(const s16x8*)(src + 0);
            s16x8 h1 = *(const s16x8*)(src + 8);
            int off = ar * 128 + aq * 32;
            *(s16x8*)((char*)As + swz(off))      = h0;
            *(s16x8*)((char*)As + swz(off + 16)) = h1;
        }
        {   // stage B
            const unsigned short* src = pT + (size_t)bn * 256 + ks + bh * 32;
            s16x8 b0 = *(const s16x8*)(src + 0);
            s16x8 b1 = *(const s16x8*)(src + 8);
            s16x8 b2 = *(const s16x8*)(src + 16);
            s16x8 b3 = *(const s16x8*)(src + 24);
            int off = bn * 128 + bh * 64;
            *(s16x8*)((char*)Bs + swz(off))      = b0;
            *(s16x8*)((char*)Bs + swz(off + 16)) = b1;
            *(s16x8*)((char*)Bs + swz(off + 32)) = b2;
            *(s16x8*)((char*)Bs + swz(off + 48)) = b3;
        }
        __syncthreads();
        #pragma unroll
        for (int kc = 0; kc < 2; ++kc) {
            s16x8 af[4], bfr[4];
            #pragma unroll
            for (int i = 0; i < 4; ++i) {
                int off = (wm * 64 + i * 16 + lr) * 128 + kc * 64 + lk * 16;
                af[i] = *(const s16x8*)((const char*)As + swz(off));
            }
            #pragma unroll
            for (int i = 0; i < 4; ++i) {
                int off = (wn * 64 + i * 16 + lr) * 128 + kc * 64 + lk * 16;
                bfr[i] = *(const s16x8*)((const char*)Bs + swz(off));
            }
            #pragma unroll
            for (int i = 0; i < 4; ++i)
                #pragma unroll
                for (int j = 0; j < 4; ++j)
                    acc[i][j] = __builtin_amdgcn_mfma_f32_16x16x32_bf16(af[i], bfr[j], acc[i][j], 0, 0, 0);
        }
        __syncthreads();
    }
    #pragma unroll
    for (int i = 0; i < 4; ++i) {
        const int mg = m0 + wm * 64 + i * 16 + lk * 4;
        #pragma unroll
        for (int j = 0; j < 4; ++j) {
            const int ng = wn * 64 + j * 16 + lr;
            const float bias = pb[ng];
            #pragma unroll
            for (int e = 0; e < 4; ++e)
                out[(size_t)(mg + e) * 256 + ng] = acc[i][j][e] + bias;
        }
    }
}

// ----------------------------------------------------------------- launch ----
extern "C" void kernel_launch(void* const* d_in, const int* in_sizes, int n_in,
                              void* d_out, int out_size, void* d_ws, size_t ws_size,
                              hipStream_t stream) {
    const float* x  = (const float*)d_in[0];
    const float* wq = (const float*)d_in[1];
    const float* qb = (const float*)d_in[2];
    const float* vb = (const float*)d_in[3];
    const float* dk = (const float*)d_in[4];
    const float* sc = (const float*)d_in[5];
    const float* w1 = (const float*)d_in[6];
    const float* b1 = (const float*)d_in[7];
    const float* w2 = (const float*)d_in[8];
    const float* pw = (const float*)d_in[9];
    const float* pb = (const float*)d_in[10];
    float* out = (float*)d_out;

    char* ws = (char*)d_ws;
    unsigned short* qkv = (unsigned short*)(ws + 0);          // 50,331,648 B (f16)
    unsigned short* att = (unsigned short*)(ws + 50331648);   // 16,777,216 B (bf16)
    unsigned int*   dkh = (unsigned int*)(ws + 67108864);     //     41,984 B
    unsigned short* wT  = (unsigned short*)(ws + 67150848);   //    393,216 B
    unsigned short* pT  = (unsigned short*)(ws + 67544064);   //    131,072 B
    float*          rlb = (float*)(ws + 67675136);            //        288 B
    float*          esc = (float*)(ws + 67675424);            //         32 B

    hipLaunchKernelGGL(k_setup, dim3(1), dim3(128), 0, stream, sc, w1, b1, w2, rlb, esc);
    hipLaunchKernelGGL(k_transpose, dim3(1065), dim3(256), 0, stream, dk, wq, pw, dkh, wT, pT);
    hipLaunchKernelGGL(k_qkv_gemm, dim3(256, 3), dim3(512), 0, stream, x, wT, qb, vb, qkv);
    hipLaunchKernelGGL(k_attn, dim3(16, 16, 8), dim3(256), 0, stream, qkv, dkh, rlb, esc, att);
    hipLaunchKernelGGL(k_proj_gemm, dim3(256), dim3(512), 0, stream, att, pT, pb, out);
}

// Round 7
// 149.723 us; speedup vs baseline: 1.5266x; 1.1449x over previous
//
#include <hip/hip_runtime.h>
#include <hip/hip_bf16.h>
#include <cstdint>
#include <cstddef>

// SlideAttention fused pipeline for MI355X (gfx950).
// B=8, H=W=64, C=256, HEADS=8, U=32, WIN=3 (9 taps), CPB=512.
//
// R7 = bisect round: k_attn reverted to the R3 known-good structure
// (1 ch/thread, fma_mix conv, DPP+swizzle red32); kept on trial:
// parallel k_setup, XCD-chunked qkv GEMM, f16 att/proj MFMA chain.

typedef __attribute__((ext_vector_type(4))) float f32x4;
typedef __attribute__((ext_vector_type(8))) short s16x8;
typedef __attribute__((ext_vector_type(4))) int   i32x4;
typedef _Float16 h2 __attribute__((ext_vector_type(2)));

#define DEVINL __device__ __forceinline__

DEVINL unsigned short f2bf(float f) {  // RNE, finite inputs only
    unsigned int u = __builtin_bit_cast(unsigned int, f);
    u += 0x7FFFu + ((u >> 16) & 1u);
    return (unsigned short)(u >> 16);
}
// LDS xor-swizzle for GEMM tiles (rows 128 B)
DEVINL int swz(int off) { return off ^ ((off >> 3) & 0x70); }

DEVINL float fexp2(float x) {
#if __has_builtin(__builtin_amdgcn_exp2f)
    return __builtin_amdgcn_exp2f(x);
#else
    return exp2f(x);
#endif
}

// ---------------------------------------------------------------- setup ----
// 576 threads: phase1 512-wide hidden layer; phase2 72x8 chunked reduce.
__global__ void k_setup(const float* __restrict__ scale,
                        const float* __restrict__ w1,
                        const float* __restrict__ b1,
                        const float* __restrict__ w2,
                        float* __restrict__ relb,
                        float* __restrict__ escale) {
    __shared__ float hbuf[512 * 9];
    __shared__ float part[8][72];
    const float LOG2E = 1.4426950408889634f;
    const int t = threadIdx.x;
    if (t < 512) {
        float wa = w1[t], wb = w1[512 + t], bb = b1[t];
        #pragma unroll
        for (int m = 0; m < 9; ++m) {
            float dy = (float)(m / 3 - 1), dx = (float)(m % 3 - 1);
            const float il8 = 0.48089834696298783f; // 1/ln(8)
            float r0 = (dy > 0.f ? 1.f : (dy < 0.f ? -1.f : 0.f)) * log1pf(fabsf(dy)) * il8;
            float r1 = (dx > 0.f ? 1.f : (dx < 0.f ? -1.f : 0.f)) * log1pf(fabsf(dx)) * il8;
            hbuf[t * 9 + m] = fmaxf(r0 * wa + r1 * wb + bb, 0.f);
        }
    }
    __syncthreads();
    {
        int chunk = t / 72, mh = t % 72;
        int m = mh / 8, head = mh % 8;
        float acc = 0.f;
        #pragma unroll 8
        for (int j = chunk * 64; j < chunk * 64 + 64; ++j)
            acc = fmaf(hbuf[j * 9 + m], w2[j * 8 + head], acc);
        part[chunk][mh] = acc;
    }
    __syncthreads();
    if (t < 72) {
        int m = t / 8, head = t % 8;
        float acc = 0.f;
        #pragma unroll
        for (int ch = 0; ch < 8; ++ch) acc += part[ch][t];
        relb[head * 9 + m] = 16.f / (1.f + expf(-acc)) * LOG2E;  // log2-domain
    } else if (t < 80) {
        escale[t - 72] = expf(scale[t - 72]) * LOG2E;            // log2-domain
    }
}

// ------------------------------------------------------------ transpose ----
__global__ void k_transpose(const float* __restrict__ dk,
                            const float* __restrict__ wq,
                            const float* __restrict__ pw,
                            unsigned int* __restrict__ dkh,
                            unsigned short* __restrict__ wT,
                            unsigned short* __restrict__ pT) {
    int i = blockIdx.x * blockDim.x + threadIdx.x;
    if (i < 10496) {       // dkh[j*256+c] = f16(dk[l=2j][c]) | f16(dk[l=2j+1][c])<<16
        int j = i >> 8, c = i & 255;
        int l0 = 2 * j, l1 = 2 * j + 1;
        float f0 = dk[((l0 / 9) * 256 + c) * 9 + (l0 % 9)];
        float f1 = (l1 < 81) ? dk[((l1 / 9) * 256 + c) * 9 + (l1 % 9)] : 0.f;
        unsigned short h0 = __builtin_bit_cast(unsigned short, (_Float16)f0);
        unsigned short h1 = __builtin_bit_cast(unsigned short, (_Float16)f1);
        dkh[i] = (unsigned int)h0 | ((unsigned int)h1 << 16);
        return;
    }
    int j = i - 10496;
    if (j < 196608) {                   // wT[n*256+k] = bf16(wq[k*768+n])
        int n = j >> 8, k = j & 255;
        wT[j] = f2bf(wq[k * 768 + n]);
        return;
    }
    int p = j - 196608;
    if (p < 65536) {                    // pT[n*256+k] = f16(pw[k*256+n])
        int n = p >> 8, k = p & 255;
        pT[p] = __builtin_bit_cast(unsigned short, (_Float16)pw[k * 256 + n]);
    }
}

// ------------------------------------------------------------- qkv GEMM ----
// 768 blocks; XCD-chunked so the 3 N-tiles of one M-tile land on one XCD L2.
__launch_bounds__(512, 1)
__global__ void k_qkv_gemm(const float* __restrict__ x,
                           const unsigned short* __restrict__ wT,
                           const float* __restrict__ qb,
                           const float* __restrict__ vb,
                           unsigned short* __restrict__ qkv) {
    __shared__ __align__(16) unsigned short As[128 * 64];
    __shared__ __align__(16) unsigned short Bs[256 * 64];
    const int orig = blockIdx.x;
    const int tile = (orig & 7) * 96 + (orig >> 3);   // 768 = 8 XCD x 96
    const int m0 = (tile / 3) * 128;
    const int n0 = (tile % 3) * 256;
    const int t = threadIdx.x;
    const int wid = t >> 6, lane = t & 63;
    const int wm = wid >> 2, wn = wid & 3;
    const int lr = lane & 15, lk = lane >> 4;
    const int ar = t >> 2, aq = t & 3;
    const int bn = t >> 1, bh = t & 1;
    f32x4 acc[4][4] = {};

    for (int ks = 0; ks < 256; ks += 64) {
        {   // stage A (f32 -> bf16)
            const float* src = x + (size_t)(m0 + ar) * 256 + ks + aq * 16;
            f32x4 v0 = *(const f32x4*)(src + 0);
            f32x4 v1 = *(const f32x4*)(src + 4);
            f32x4 v2 = *(const f32x4*)(src + 8);
            f32x4 v3 = *(const f32x4*)(src + 12);
            s16x8 h0, h1;
            h0[0]=(short)f2bf(v0[0]); h0[1]=(short)f2bf(v0[1]); h0[2]=(short)f2bf(v0[2]); h0[3]=(short)f2bf(v0[3]);
            h0[4]=(short)f2bf(v1[0]); h0[5]=(short)f2bf(v1[1]); h0[6]=(short)f2bf(v1[2]); h0[7]=(short)f2bf(v1[3]);
            h1[0]=(short)f2bf(v2[0]); h1[1]=(short)f2bf(v2[1]); h1[2]=(short)f2bf(v2[2]); h1[3]=(short)f2bf(v2[3]);
            h1[4]=(short)f2bf(v3[0]); h1[5]=(short)f2bf(v3[1]); h1[6]=(short)f2bf(v3[2]); h1[7]=(short)f2bf(v3[3]);
            int off = ar * 128 + aq * 32;
            *(s16x8*)((char*)As + swz(off))      = h0;
            *(s16x8*)((char*)As + swz(off + 16)) = h1;
        }
        {   // stage B (already bf16, K-major)
            const unsigned short* src = wT + (size_t)(n0 + bn) * 256 + ks + bh * 32;
            s16x8 b0 = *(const s16x8*)(src + 0);
            s16x8 b1 = *(const s16x8*)(src + 8);
            s16x8 b2 = *(const s16x8*)(src + 16);
            s16x8 b3 = *(const s16x8*)(src + 24);
            int off = bn * 128 + bh * 64;
            *(s16x8*)((char*)Bs + swz(off))      = b0;
            *(s16x8*)((char*)Bs + swz(off + 16)) = b1;
            *(s16x8*)((char*)Bs + swz(off + 32)) = b2;
            *(s16x8*)((char*)Bs + swz(off + 48)) = b3;
        }
        __syncthreads();
        #pragma unroll
        for (int kc = 0; kc < 2; ++kc) {
            s16x8 af[4], bfr[4];
            #pragma unroll
            for (int i = 0; i < 4; ++i) {
                int off = (wm * 64 + i * 16 + lr) * 128 + kc * 64 + lk * 16;
                af[i] = *(const s16x8*)((const char*)As + swz(off));
            }
            #pragma unroll
            for (int i = 0; i < 4; ++i) {
                int off = (wn * 64 + i * 16 + lr) * 128 + kc * 64 + lk * 16;
                bfr[i] = *(const s16x8*)((const char*)Bs + swz(off));
            }
            #pragma unroll
            for (int i = 0; i < 4; ++i)
                #pragma unroll
                for (int j = 0; j < 4; ++j)
                    acc[i][j] = __builtin_amdgcn_mfma_f32_16x16x32_bf16(af[i], bfr[j], acc[i][j], 0, 0, 0);
        }
        __syncthreads();
    }
    #pragma unroll
    for (int i = 0; i < 4; ++i) {
        const int mg = m0 + wm * 64 + i * 16 + lk * 4;
        #pragma unroll
        for (int j = 0; j < 4; ++j) {
            const int ng = n0 + wn * 64 + j * 16 + lr;
            float bias = (ng < 256) ? qb[ng] : ((ng < 512) ? 0.f : vb[ng - 512]);
            #pragma unroll
            for (int e = 0; e < 4; ++e)
                qkv[(size_t)(mg + e) * 768 + ng] =
                    __builtin_bit_cast(unsigned short, (_Float16)(acc[i][j][e] + bias));
        }
    }
}

// ------------------------------------------------- fused conv + attention ----
// R3 known-good structure: 4x4 pixel tile, 256 threads = 1 thread/channel.
// dk weights: 41 packed-f16 VGPRs consumed via v_fma_mix.
// k/v halo interleaved (one u32/channel) in LDS (36.9 KB).
// 32-lane reductions: 4x DPP-fused adds + 1 ds_swizzle(xor16).

template <int CTRL>
DEVINL float dpp_add(float x) {
    int r = __builtin_amdgcn_update_dpp(0, __builtin_bit_cast(int, x),
                                        CTRL, 0xF, 0xF, true);
    return x + __builtin_bit_cast(float, r);
}
DEVINL float red32(float x) {
    x = dpp_add<0xB1>(x);   // quad_perm [1,0,3,2]  : xor1
    x = dpp_add<0x4E>(x);   // quad_perm [2,3,0,1]  : xor2
    x = dpp_add<0x141>(x);  // row_half_mirror      : xor within 8
    x = dpp_add<0x140>(x);  // row_mirror           : xor within 16
    int s = __builtin_amdgcn_ds_swizzle(__builtin_bit_cast(int, x), 0x401F); // xor16
    return x + __builtin_bit_cast(float, s);
}

__launch_bounds__(256, 2)
__global__ void k_attn(const unsigned short* __restrict__ qkv,
                       const unsigned int* __restrict__ dkh,
                       const float* __restrict__ relb,
                       const float* __restrict__ escale,
                       unsigned short* __restrict__ att) {
    __shared__ __align__(16) unsigned int kv[36 * 256];   // (k | v<<16) f16 pair
    const int t = threadIdx.x;
    const int c = t;
    const int head = c >> 5;
    const int w0 = blockIdx.x * 4, h0 = blockIdx.y * 4, b = blockIdx.z;

    h2 wv[41];
    #pragma unroll
    for (int j = 0; j < 41; ++j) wv[j] = __builtin_bit_cast(h2, dkh[j * 256 + c]);
    float rb[9];
    #pragma unroll
    for (int m = 0; m < 9; ++m) rb[m] = relb[head * 9 + m];
    const float es2 = escale[head];          // exp(scale)*log2e

    // stage k/v halo, interleaved via v_perm: 36 px x 32 8-channel groups
    for (int idx = t; idx < 36 * 32; idx += 256) {
        int hp = idx >> 5, ch = idx & 31;
        int hy = h0 - 1 + hp / 6, hx = w0 - 1 + hp % 6;
        i32x4 kk = {0, 0, 0, 0}, vv = {0, 0, 0, 0};
        if ((unsigned)hy < 64u && (unsigned)hx < 64u) {
            const unsigned short* base = qkv + ((size_t)((b * 64 + hy) * 64 + hx)) * 768;
            kk = *(const i32x4*)(base + 256 + ch * 8);
            vv = *(const i32x4*)(base + 512 + ch * 8);
        }
        i32x4 p0, p1;
        #pragma unroll
        for (int e = 0; e < 4; ++e) {
            unsigned lo = __builtin_amdgcn_perm((unsigned)vv[e], (unsigned)kk[e], 0x05040100u);
            unsigned hi = __builtin_amdgcn_perm((unsigned)vv[e], (unsigned)kk[e], 0x07060302u);
            if (e < 2) { p0[2 * e] = (int)lo; p0[2 * e + 1] = (int)hi; }
            else       { p1[2 * (e - 2)] = (int)lo; p1[2 * (e - 2) + 1] = (int)hi; }
        }
        *(i32x4*)(kv + hp * 256 + ch * 8)     = p0;
        *(i32x4*)(kv + hp * 256 + ch * 8 + 4) = p1;
    }
    __syncthreads();

    for (int p = 0; p < 16; ++p) {
        const int py = p >> 2, px = p & 3;
        const int iy = h0 + py, ix = w0 + px;
        const float qv = (float)__builtin_bit_cast(_Float16,
            qkv[((size_t)((b * 64 + iy) * 64 + ix)) * 768 + c]);

        h2 kvp[9];
        #pragma unroll
        for (int ij = 0; ij < 9; ++ij)
            kvp[ij] = __builtin_bit_cast(h2,
                kv[((py + ij / 3) * 6 + (px + ij % 3)) * 256 + c]);

        float ko[9], vo[9];
        #pragma unroll
        for (int m = 0; m < 9; ++m) {      // identity tap (weight == 1.0)
            ko[m] = (float)kvp[m].x;
            vo[m] = (float)kvp[m].y;
        }
        #pragma unroll
        for (int ij = 0; ij < 9; ++ij)
            #pragma unroll
            for (int m = 0; m < 9; ++m)
                if (ij != m) {
                    const int l = ij * 9 + m;
                    if (l & 1) {
                        ko[m] = fmaf((float)kvp[ij].x, (float)wv[l >> 1].y, ko[m]);
                        vo[m] = fmaf((float)kvp[ij].y, (float)wv[l >> 1].y, vo[m]);
                    } else {
                        ko[m] = fmaf((float)kvp[ij].x, (float)wv[l >> 1].x, ko[m]);
                        vo[m] = fmaf((float)kvp[ij].y, (float)wv[l >> 1].x, vo[m]);
                    }
                }

        float red[19];
        red[0] = qv * qv;
        #pragma unroll
        for (int m = 0; m < 9; ++m) {
            red[1 + m]  = qv * ko[m];
            red[10 + m] = ko[m] * ko[m];
        }
        #pragma unroll
        for (int i = 0; i < 19; ++i) red[i] = red32(red[i]);

        const float rq = __builtin_amdgcn_rsqf(fmaxf(red[0], 1.55e-5f)) * es2;
        const bool yt = (iy == 0), yb = (iy == 63), xl = (ix == 0), xr = (ix == 63);
        const float NEG = -144.2695040888963f;  // -100*log2e
        float a[9];
        #pragma unroll
        for (int m = 0; m < 9; ++m) {
            float rk = __builtin_amdgcn_rsqf(fmaxf(red[10 + m], 1.55e-5f));
            int dy = m / 3 - 1, dx = m % 3 - 1;
            bool oob = (dy < 0 && yt) || (dy > 0 && yb) || (dx < 0 && xl) || (dx > 0 && xr);
            a[m] = red[1 + m] * rq * rk + rb[m] + (oob ? NEG : 0.f);
        }
        float sum = 0.f, o = 0.f;   // no max-subtract: a in [-182, 38], exp2 safe
        #pragma unroll
        for (int m = 0; m < 9; ++m) {
            float e = fexp2(a[m]);
            sum += e;
            o = fmaf(e, vo[m], o);
        }
        o *= __builtin_amdgcn_rcpf(sum);
        att[((size_t)((b * 64 + iy) * 64 + ix)) * 256 + c] =
            __builtin_bit_cast(unsigned short, (_Float16)o);   // f16 (was bf16)
    }
}

// ------------------------------------------------------------- proj GEMM ----
__launch_bounds__(512, 1)
__global__ void k_proj_gemm(const unsigned short* __restrict__ attin,
                            const unsigned short* __restrict__ pT,
                            const float* __restrict__ pb,
                            float* __restrict__ out) {
    __shared__ __align__(16) unsigned short As[128 * 64];
    __shared__ __align__(16) unsigned short Bs[256 * 64];
    const int t = threadIdx.x;
    const int m0 = blockIdx.x * 128;
    const int wid = t >> 6, lane = t & 63;
    const int wm = wid >> 2, wn = wid & 3;
    const int lr = lane & 15, lk = lane >> 4;
    const int ar = t >> 2, aq = t & 3;
    const int bn = t >> 1, bh = t & 1;
    f32x4 acc[4][4] = {};

    for (int ks = 0; ks < 256; ks += 64) {
        {   // stage A (f16 rows of att)
            const unsigned short* src = attin + (size_t)(m0 + ar) * 256 + ks + aq * 16;
            s16x8 h0 = *(const s16x8*)(src + 0);
            s16x8 h1 = *(const s16x8*)(src + 8);
            int off = ar * 128 + aq * 32;
            *(s16x8*)((char*)As + swz(off))      = h0;
            *(s16x8*)((char*)As + swz(off + 16)) = h1;
        }
        {   // stage B (f16)
            const unsigned short* src = pT + (size_t)bn * 256 + ks + bh * 32;
            s16x8 b0 = *(const s16x8*)(src + 0);
            s16x8 b1 = *(const s16x8*)(src + 8);
            s16x8 b2 = *(const s16x8*)(src + 16);
            s16x8 b3 = *(const s16x8*)(src + 24);
            int off = bn * 128 + bh * 64;
            *(s16x8*)((char*)Bs + swz(off))      = b0;
            *(s16x8*)((char*)Bs + swz(off + 16)) = b1;
            *(s16x8*)((char*)Bs + swz(off + 32)) = b2;
            *(s16x8*)((char*)Bs + swz(off + 48)) = b3;
        }
        __syncthreads();
        #pragma unroll
        for (int kc = 0; kc < 2; ++kc) {
            s16x8 af[4], bfr[4];
            #pragma unroll
            for (int i = 0; i < 4; ++i) {
                int off = (wm * 64 + i * 16 + lr) * 128 + kc * 64 + lk * 16;
                af[i] = *(const s16x8*)((const char*)As + swz(off));
            }
            #pragma unroll
            for (int i = 0; i < 4; ++i) {
                int off = (wn * 64 + i * 16 + lr) * 128 + kc * 64 + lk * 16;
                bfr[i] = *(const s16x8*)((const char*)Bs + swz(off));
            }
            #pragma unroll
            for (int i = 0; i < 4; ++i)
                #pragma unroll
                for (int j = 0; j < 4; ++j)
                    acc[i][j] = __builtin_amdgcn_mfma_f32_16x16x32_f16(af[i], bfr[j], acc[i][j], 0, 0, 0);
        }
        __syncthreads();
    }
    #pragma unroll
    for (int i = 0; i < 4; ++i) {
        const int mg = m0 + wm * 64 + i * 16 + lk * 4;
        #pragma unroll
        for (int j = 0; j < 4; ++j) {
            const int ng = wn * 64 + j * 16 + lr;
            const float bias = pb[ng];
            #pragma unroll
            for (int e = 0; e < 4; ++e)
                out[(size_t)(mg + e) * 256 + ng] = acc[i][j][e] + bias;
        }
    }
}

// ----------------------------------------------------------------- launch ----
extern "C" void kernel_launch(void* const* d_in, const int* in_sizes, int n_in,
                              void* d_out, int out_size, void* d_ws, size_t ws_size,
                              hipStream_t stream) {
    const float* x  = (const float*)d_in[0];
    const float* wq = (const float*)d_in[1];
    const float* qb = (const float*)d_in[2];
    const float* vb = (const float*)d_in[3];
    const float* dk = (const float*)d_in[4];
    const float* sc = (const float*)d_in[5];
    const float* w1 = (const float*)d_in[6];
    const float* b1 = (const float*)d_in[7];
    const float* w2 = (const float*)d_in[8];
    const float* pw = (const float*)d_in[9];
    const float* pb = (const float*)d_in[10];
    float* out = (float*)d_out;

    char* ws = (char*)d_ws;
    unsigned short* qkv = (unsigned short*)(ws + 0);          // 50,331,648 B (f16)
    unsigned short* att = (unsigned short*)(ws + 50331648);   // 16,777,216 B (f16)
    unsigned int*   dkh = (unsigned int*)(ws + 67108864);     //     41,984 B
    unsigned short* wT  = (unsigned short*)(ws + 67150848);   //    393,216 B (bf16)
    unsigned short* pT  = (unsigned short*)(ws + 67544064);   //    131,072 B (f16)
    float*          rlb = (float*)(ws + 67675136);            //        288 B
    float*          esc = (float*)(ws + 67675424);            //         32 B

    hipLaunchKernelGGL(k_setup, dim3(1), dim3(576), 0, stream, sc, w1, b1, w2, rlb, esc);
    hipLaunchKernelGGL(k_transpose, dim3(1065), dim3(256), 0, stream, dk, wq, pw, dkh, wT, pT);
    hipLaunchKernelGGL(k_qkv_gemm, dim3(768), dim3(512), 0, stream, x, wT, qb, vb, qkv);
    hipLaunchKernelGGL(k_attn, dim3(16, 16, 8), dim3(256), 0, stream, qkv, dkh, rlb, esc, att);
    hipLaunchKernelGGL(k_proj_gemm, dim3(256), dim3(512), 0, stream, att, pT, pb, out);
}

// Round 9
// 135.444 us; speedup vs baseline: 1.6876x; 1.1054x over previous
//
#include <hip/hip_runtime.h>
#include <hip/hip_bf16.h>
#include <cstdint>
#include <cstddef>

// SlideAttention fused pipeline for MI355X (gfx950).
// B=8, H=W=64, C=256, HEADS=8, U=32, WIN=3 (9 taps), CPB=512.
//
// R9 = R8 (packed-f16 conv) with the shufflevector const-index fix:
// weight splat selected by an unroll-time-constant branch.

typedef __attribute__((ext_vector_type(4))) float f32x4;
typedef __attribute__((ext_vector_type(8))) short s16x8;
typedef __attribute__((ext_vector_type(4))) int   i32x4;
typedef _Float16 h2 __attribute__((ext_vector_type(2)));

#define DEVINL __device__ __forceinline__

DEVINL unsigned short f2bf(float f) {  // RNE, finite inputs only
    unsigned int u = __builtin_bit_cast(unsigned int, f);
    u += 0x7FFFu + ((u >> 16) & 1u);
    return (unsigned short)(u >> 16);
}
// LDS xor-swizzle for GEMM tiles (rows 128 B)
DEVINL int swz(int off) { return off ^ ((off >> 3) & 0x70); }

DEVINL float fexp2(float x) {
#if __has_builtin(__builtin_amdgcn_exp2f)
    return __builtin_amdgcn_exp2f(x);
#else
    return exp2f(x);
#endif
}

// ---------------------------------------------------------------- setup ----
// 576 threads: phase1 512-wide hidden layer; phase2 72x8 chunked reduce.
__global__ void k_setup(const float* __restrict__ scale,
                        const float* __restrict__ w1,
                        const float* __restrict__ b1,
                        const float* __restrict__ w2,
                        float* __restrict__ relb,
                        float* __restrict__ escale) {
    __shared__ float hbuf[512 * 9];
    __shared__ float part[8][72];
    const float LOG2E = 1.4426950408889634f;
    const int t = threadIdx.x;
    if (t < 512) {
        float wa = w1[t], wb = w1[512 + t], bb = b1[t];
        #pragma unroll
        for (int m = 0; m < 9; ++m) {
            float dy = (float)(m / 3 - 1), dx = (float)(m % 3 - 1);
            const float il8 = 0.48089834696298783f; // 1/ln(8)
            float r0 = (dy > 0.f ? 1.f : (dy < 0.f ? -1.f : 0.f)) * log1pf(fabsf(dy)) * il8;
            float r1 = (dx > 0.f ? 1.f : (dx < 0.f ? -1.f : 0.f)) * log1pf(fabsf(dx)) * il8;
            hbuf[t * 9 + m] = fmaxf(r0 * wa + r1 * wb + bb, 0.f);
        }
    }
    __syncthreads();
    {
        int chunk = t / 72, mh = t % 72;
        int m = mh / 8, head = mh % 8;
        float acc = 0.f;
        #pragma unroll 8
        for (int j = chunk * 64; j < chunk * 64 + 64; ++j)
            acc = fmaf(hbuf[j * 9 + m], w2[j * 8 + head], acc);
        part[chunk][mh] = acc;
    }
    __syncthreads();
    if (t < 72) {
        int m = t / 8, head = t % 8;
        float acc = 0.f;
        #pragma unroll
        for (int ch = 0; ch < 8; ++ch) acc += part[ch][t];
        relb[head * 9 + m] = 16.f / (1.f + expf(-acc)) * LOG2E;  // log2-domain
    } else if (t < 80) {
        escale[t - 72] = expf(scale[t - 72]) * LOG2E;            // log2-domain
    }
}

// ------------------------------------------------------------ transpose ----
__global__ void k_transpose(const float* __restrict__ dk,
                            const float* __restrict__ wq,
                            const float* __restrict__ pw,
                            unsigned int* __restrict__ dkh,
                            unsigned short* __restrict__ wT,
                            unsigned short* __restrict__ pT) {
    int i = blockIdx.x * blockDim.x + threadIdx.x;
    if (i < 10496) {       // dkh[j*256+c] = f16(dk[l=2j][c]) | f16(dk[l=2j+1][c])<<16
        int j = i >> 8, c = i & 255;
        int l0 = 2 * j, l1 = 2 * j + 1;
        float f0 = dk[((l0 / 9) * 256 + c) * 9 + (l0 % 9)];
        float f1 = (l1 < 81) ? dk[((l1 / 9) * 256 + c) * 9 + (l1 % 9)] : 0.f;
        unsigned short h0 = __builtin_bit_cast(unsigned short, (_Float16)f0);
        unsigned short h1 = __builtin_bit_cast(unsigned short, (_Float16)f1);
        dkh[i] = (unsigned int)h0 | ((unsigned int)h1 << 16);
        return;
    }
    int j = i - 10496;
    if (j < 196608) {                   // wT[n*256+k] = bf16(wq[k*768+n])
        int n = j >> 8, k = j & 255;
        wT[j] = f2bf(wq[k * 768 + n]);
        return;
    }
    int p = j - 196608;
    if (p < 65536) {                    // pT[n*256+k] = f16(pw[k*256+n])
        int n = p >> 8, k = p & 255;
        pT[p] = __builtin_bit_cast(unsigned short, (_Float16)pw[k * 256 + n]);
    }
}

// ------------------------------------------------------------- qkv GEMM ----
// 768 blocks; XCD-chunked so the 3 N-tiles of one M-tile land on one XCD L2.
__launch_bounds__(512, 1)
__global__ void k_qkv_gemm(const float* __restrict__ x,
                           const unsigned short* __restrict__ wT,
                           const float* __restrict__ qb,
                           const float* __restrict__ vb,
                           unsigned short* __restrict__ qkv) {
    __shared__ __align__(16) unsigned short As[128 * 64];
    __shared__ __align__(16) unsigned short Bs[256 * 64];
    const int orig = blockIdx.x;
    const int tile = (orig & 7) * 96 + (orig >> 3);   // 768 = 8 XCD x 96
    const int m0 = (tile / 3) * 128;
    const int n0 = (tile % 3) * 256;
    const int t = threadIdx.x;
    const int wid = t >> 6, lane = t & 63;
    const int wm = wid >> 2, wn = wid & 3;
    const int lr = lane & 15, lk = lane >> 4;
    const int ar = t >> 2, aq = t & 3;
    const int bn = t >> 1, bh = t & 1;
    f32x4 acc[4][4] = {};

    for (int ks = 0; ks < 256; ks += 64) {
        {   // stage A (f32 -> bf16)
            const float* src = x + (size_t)(m0 + ar) * 256 + ks + aq * 16;
            f32x4 v0 = *(const f32x4*)(src + 0);
            f32x4 v1 = *(const f32x4*)(src + 4);
            f32x4 v2 = *(const f32x4*)(src + 8);
            f32x4 v3 = *(const f32x4*)(src + 12);
            s16x8 h0, h1;
            h0[0]=(short)f2bf(v0[0]); h0[1]=(short)f2bf(v0[1]); h0[2]=(short)f2bf(v0[2]); h0[3]=(short)f2bf(v0[3]);
            h0[4]=(short)f2bf(v1[0]); h0[5]=(short)f2bf(v1[1]); h0[6]=(short)f2bf(v1[2]); h0[7]=(short)f2bf(v1[3]);
            h1[0]=(short)f2bf(v2[0]); h1[1]=(short)f2bf(v2[1]); h1[2]=(short)f2bf(v2[2]); h1[3]=(short)f2bf(v2[3]);
            h1[4]=(short)f2bf(v3[0]); h1[5]=(short)f2bf(v3[1]); h1[6]=(short)f2bf(v3[2]); h1[7]=(short)f2bf(v3[3]);
            int off = ar * 128 + aq * 32;
            *(s16x8*)((char*)As + swz(off))      = h0;
            *(s16x8*)((char*)As + swz(off + 16)) = h1;
        }
        {   // stage B (already bf16, K-major)
            const unsigned short* src = wT + (size_t)(n0 + bn) * 256 + ks + bh * 32;
            s16x8 b0 = *(const s16x8*)(src + 0);
            s16x8 b1 = *(const s16x8*)(src + 8);
            s16x8 b2 = *(const s16x8*)(src + 16);
            s16x8 b3 = *(const s16x8*)(src + 24);
            int off = bn * 128 + bh * 64;
            *(s16x8*)((char*)Bs + swz(off))      = b0;
            *(s16x8*)((char*)Bs + swz(off + 16)) = b1;
            *(s16x8*)((char*)Bs + swz(off + 32)) = b2;
            *(s16x8*)((char*)Bs + swz(off + 48)) = b3;
        }
        __syncthreads();
        #pragma unroll
        for (int kc = 0; kc < 2; ++kc) {
            s16x8 af[4], bfr[4];
            #pragma unroll
            for (int i = 0; i < 4; ++i) {
                int off = (wm * 64 + i * 16 + lr) * 128 + kc * 64 + lk * 16;
                af[i] = *(const s16x8*)((const char*)As + swz(off));
            }
            #pragma unroll
            for (int i = 0; i < 4; ++i) {
                int off = (wn * 64 + i * 16 + lr) * 128 + kc * 64 + lk * 16;
                bfr[i] = *(const s16x8*)((const char*)Bs + swz(off));
            }
            #pragma unroll
            for (int i = 0; i < 4; ++i)
                #pragma unroll
                for (int j = 0; j < 4; ++j)
                    acc[i][j] = __builtin_amdgcn_mfma_f32_16x16x32_bf16(af[i], bfr[j], acc[i][j], 0, 0, 0);
        }
        __syncthreads();
    }
    #pragma unroll
    for (int i = 0; i < 4; ++i) {
        const int mg = m0 + wm * 64 + i * 16 + lk * 4;
        #pragma unroll
        for (int j = 0; j < 4; ++j) {
            const int ng = n0 + wn * 64 + j * 16 + lr;
            float bias = (ng < 256) ? qb[ng] : ((ng < 512) ? 0.f : vb[ng - 512]);
            #pragma unroll
            for (int e = 0; e < 4; ++e)
                qkv[(size_t)(mg + e) * 768 + ng] =
                    __builtin_bit_cast(unsigned short, (_Float16)(acc[i][j][e] + bias));
        }
    }
}

// ------------------------------------------------- fused conv + attention ----
// 4x4 pixel tile, 256 threads = 1 thread/channel.
// dk weights: 41 packed-f16 VGPRs; conv = 72 v_pk_fma_f16 on the (k|v) h2
// pair (weight splat via constant-index shuffles chosen at unroll time).
// 32-lane reductions: 4x DPP-fused adds + 1 ds_swizzle(xor16), f32.

template <int CTRL>
DEVINL float dpp_add(float x) {
    int r = __builtin_amdgcn_update_dpp(0, __builtin_bit_cast(int, x),
                                        CTRL, 0xF, 0xF, true);
    return x + __builtin_bit_cast(float, r);
}
DEVINL float red32(float x) {
    x = dpp_add<0xB1>(x);   // quad_perm [1,0,3,2]  : xor1
    x = dpp_add<0x4E>(x);   // quad_perm [2,3,0,1]  : xor2
    x = dpp_add<0x141>(x);  // row_half_mirror      : xor within 8
    x = dpp_add<0x140>(x);  // row_mirror           : xor within 16
    int s = __builtin_amdgcn_ds_swizzle(__builtin_bit_cast(int, x), 0x401F); // xor16
    return x + __builtin_bit_cast(float, s);
}

__launch_bounds__(256, 2)
__global__ void k_attn(const unsigned short* __restrict__ qkv,
                       const unsigned int* __restrict__ dkh,
                       const float* __restrict__ relb,
                       const float* __restrict__ escale,
                       unsigned short* __restrict__ att) {
    __shared__ __align__(16) unsigned int kv[36 * 256];   // (k | v<<16) f16 pair
    const int t = threadIdx.x;
    const int c = t;
    const int head = c >> 5;
    const int w0 = blockIdx.x * 4, h0 = blockIdx.y * 4, b = blockIdx.z;

    h2 wv[41];
    #pragma unroll
    for (int j = 0; j < 41; ++j) wv[j] = __builtin_bit_cast(h2, dkh[j * 256 + c]);
    float rb[9];
    #pragma unroll
    for (int m = 0; m < 9; ++m) rb[m] = relb[head * 9 + m];
    const float es2 = escale[head];          // exp(scale)*log2e

    // stage k/v halo, interleaved via v_perm: 36 px x 32 8-channel groups
    for (int idx = t; idx < 36 * 32; idx += 256) {
        int hp = idx >> 5, ch = idx & 31;
        int hy = h0 - 1 + hp / 6, hx = w0 - 1 + hp % 6;
        i32x4 kk = {0, 0, 0, 0}, vv = {0, 0, 0, 0};
        if ((unsigned)hy < 64u && (unsigned)hx < 64u) {
            const unsigned short* base = qkv + ((size_t)((b * 64 + hy) * 64 + hx)) * 768;
            kk = *(const i32x4*)(base + 256 + ch * 8);
            vv = *(const i32x4*)(base + 512 + ch * 8);
        }
        i32x4 p0, p1;
        #pragma unroll
        for (int e = 0; e < 4; ++e) {
            unsigned lo = __builtin_amdgcn_perm((unsigned)vv[e], (unsigned)kk[e], 0x05040100u);
            unsigned hi = __builtin_amdgcn_perm((unsigned)vv[e], (unsigned)kk[e], 0x07060302u);
            if (e < 2) { p0[2 * e] = (int)lo; p0[2 * e + 1] = (int)hi; }
            else       { p1[2 * (e - 2)] = (int)lo; p1[2 * (e - 2) + 1] = (int)hi; }
        }
        *(i32x4*)(kv + hp * 256 + ch * 8)     = p0;
        *(i32x4*)(kv + hp * 256 + ch * 8 + 4) = p1;
    }
    __syncthreads();

    for (int p = 0; p < 16; ++p) {
        const int py = p >> 2, px = p & 3;
        const int iy = h0 + py, ix = w0 + px;
        const float qv = (float)__builtin_bit_cast(_Float16,
            qkv[((size_t)((b * 64 + iy) * 64 + ix)) * 768 + c]);

        h2 kvp[9];
        #pragma unroll
        for (int ij = 0; ij < 9; ++ij)
            kvp[ij] = __builtin_bit_cast(h2,
                kv[((py + ij / 3) * 6 + (px + ij % 3)) * 256 + c]);

        // conv: packed (k|v) accumulate, one v_pk_fma_f16 per non-identity tap
        h2 acc2[9];
        #pragma unroll
        for (int m = 0; m < 9; ++m) acc2[m] = kvp[m];   // identity tap (w == 1)
        #pragma unroll
        for (int ij = 0; ij < 9; ++ij)
            #pragma unroll
            for (int m = 0; m < 9; ++m)
                if (ij != m) {
                    const int l = ij * 9 + m;
                    h2 w = wv[l >> 1];
                    h2 wsp = (l & 1) ? __builtin_shufflevector(w, w, 1, 1)
                                     : __builtin_shufflevector(w, w, 0, 0);
                    acc2[m] = __builtin_elementwise_fma(kvp[ij], wsp, acc2[m]);
                }
        float ko[9], vo[9];
        #pragma unroll
        for (int m = 0; m < 9; ++m) {
            ko[m] = (float)acc2[m].x;
            vo[m] = (float)acc2[m].y;
        }

        float red[19];
        red[0] = qv * qv;
        #pragma unroll
        for (int m = 0; m < 9; ++m) {
            red[1 + m]  = qv * ko[m];
            red[10 + m] = ko[m] * ko[m];
        }
        #pragma unroll
        for (int i = 0; i < 19; ++i) red[i] = red32(red[i]);

        const float rq = __builtin_amdgcn_rsqf(fmaxf(red[0], 1.55e-5f)) * es2;
        const bool yt = (iy == 0), yb = (iy == 63), xl = (ix == 0), xr = (ix == 63);
        const float NEG = -144.2695040888963f;  // -100*log2e
        float a[9];
        #pragma unroll
        for (int m = 0; m < 9; ++m) {
            float rk = __builtin_amdgcn_rsqf(fmaxf(red[10 + m], 1.55e-5f));
            int dy = m / 3 - 1, dx = m % 3 - 1;
            bool oob = (dy < 0 && yt) || (dy > 0 && yb) || (dx < 0 && xl) || (dx > 0 && xr);
            a[m] = red[1 + m] * rq * rk + rb[m] + (oob ? NEG : 0.f);
        }
        float sum = 0.f, o = 0.f;   // no max-subtract: a in [-182, 38], exp2 safe
        #pragma unroll
        for (int m = 0; m < 9; ++m) {
            float e = fexp2(a[m]);
            sum += e;
            o = fmaf(e, vo[m], o);
        }
        o *= __builtin_amdgcn_rcpf(sum);
        att[((size_t)((b * 64 + iy) * 64 + ix)) * 256 + c] =
            __builtin_bit_cast(unsigned short, (_Float16)o);   // f16
    }
}

// ------------------------------------------------------------- proj GEMM ----
__launch_bounds__(512, 1)
__global__ void k_proj_gemm(const unsigned short* __restrict__ attin,
                            const unsigned short* __restrict__ pT,
                            const float* __restrict__ pb,
                            float* __restrict__ out) {
    __shared__ __align__(16) unsigned short As[128 * 64];
    __shared__ __align__(16) unsigned short Bs[256 * 64];
    const int t = threadIdx.x;
    const int m0 = blockIdx.x * 128;
    const int wid = t >> 6, lane = t & 63;
    const int wm = wid >> 2, wn = wid & 3;
    const int lr = lane & 15, lk = lane >> 4;
    const int ar = t >> 2, aq = t & 3;
    const int bn = t >> 1, bh = t & 1;
    f32x4 acc[4][4] = {};

    for (int ks = 0; ks < 256; ks += 64) {
        {   // stage A (f16 rows of att)
            const unsigned short* src = attin + (size_t)(m0 + ar) * 256 + ks + aq * 16;
            s16x8 h0 = *(const s16x8*)(src + 0);
            s16x8 h1 = *(const s16x8*)(src + 8);
            int off = ar * 128 + aq * 32;
            *(s16x8*)((char*)As + swz(off))      = h0;
            *(s16x8*)((char*)As + swz(off + 16)) = h1;
        }
        {   // stage B (f16)
            const unsigned short* src = pT + (size_t)bn * 256 + ks + bh * 32;
            s16x8 b0 = *(const s16x8*)(src + 0);
            s16x8 b1 = *(const s16x8*)(src + 8);
            s16x8 b2 = *(const s16x8*)(src + 16);
            s16x8 b3 = *(const s16x8*)(src + 24);
            int off = bn * 128 + bh * 64;
            *(s16x8*)((char*)Bs + swz(off))      = b0;
            *(s16x8*)((char*)Bs + swz(off + 16)) = b1;
            *(s16x8*)((char*)Bs + swz(off + 32)) = b2;
            *(s16x8*)((char*)Bs + swz(off + 48)) = b3;
        }
        __syncthreads();
        #pragma unroll
        for (int kc = 0; kc < 2; ++kc) {
            s16x8 af[4], bfr[4];
            #pragma unroll
            for (int i = 0; i < 4; ++i) {
                int off = (wm * 64 + i * 16 + lr) * 128 + kc * 64 + lk * 16;
                af[i] = *(const s16x8*)((const char*)As + swz(off));
            }
            #pragma unroll
            for (int i = 0; i < 4; ++i) {
                int off = (wn * 64 + i * 16 + lr) * 128 + kc * 64 + lk * 16;
                bfr[i] = *(const s16x8*)((const char*)Bs + swz(off));
            }
            #pragma unroll
            for (int i = 0; i < 4; ++i)
                #pragma unroll
                for (int j = 0; j < 4; ++j)
                    acc[i][j] = __builtin_amdgcn_mfma_f32_16x16x32_f16(af[i], bfr[j], acc[i][j], 0, 0, 0);
        }
        __syncthreads();
    }
    #pragma unroll
    for (int i = 0; i < 4; ++i) {
        const int mg = m0 + wm * 64 + i * 16 + lk * 4;
        #pragma unroll
        for (int j = 0; j < 4; ++j) {
            const int ng = wn * 64 + j * 16 + lr;
            const float bias = pb[ng];
            #pragma unroll
            for (int e = 0; e < 4; ++e)
                out[(size_t)(mg + e) * 256 + ng] = acc[i][j][e] + bias;
        }
    }
}

// ----------------------------------------------------------------- launch ----
extern "C" void kernel_launch(void* const* d_in, const int* in_sizes, int n_in,
                              void* d_out, int out_size, void* d_ws, size_t ws_size,
                              hipStream_t stream) {
    const float* x  = (const float*)d_in[0];
    const float* wq = (const float*)d_in[1];
    const float* qb = (const float*)d_in[2];
    const float* vb = (const float*)d_in[3];
    const float* dk = (const float*)d_in[4];
    const float* sc = (const float*)d_in[5];
    const float* w1 = (const float*)d_in[6];
    const float* b1 = (const float*)d_in[7];
    const float* w2 = (const float*)d_in[8];
    const float* pw = (const float*)d_in[9];
    const float* pb = (const float*)d_in[10];
    float* out = (float*)d_out;

    char* ws = (char*)d_ws;
    unsigned short* qkv = (unsigned short*)(ws + 0);          // 50,331,648 B (f16)
    unsigned short* att = (unsigned short*)(ws + 50331648);   // 16,777,216 B (f16)
    unsigned int*   dkh = (unsigned int*)(ws + 67108864);     //     41,984 B
    unsigned short* wT  = (unsigned short*)(ws + 67150848);   //    393,216 B (bf16)
    unsigned short* pT  = (unsigned short*)(ws + 67544064);   //    131,072 B (f16)
    float*          rlb = (float*)(ws + 67675136);            //        288 B
    float*          esc = (float*)(ws + 67675424);            //         32 B

    hipLaunchKernelGGL(k_setup, dim3(1), dim3(576), 0, stream, sc, w1, b1, w2, rlb, esc);
    hipLaunchKernelGGL(k_transpose, dim3(1065), dim3(256), 0, stream, dk, wq, pw, dkh, wT, pT);
    hipLaunchKernelGGL(k_qkv_gemm, dim3(768), dim3(512), 0, stream, x, wT, qb, vb, qkv);
    hipLaunchKernelGGL(k_attn, dim3(16, 16, 8), dim3(256), 0, stream, qkv, dkh, rlb, esc, att);
    hipLaunchKernelGGL(k_proj_gemm, dim3(256), dim3(512), 0, stream, att, pT, pb, out);
}

// Round 10
// 107.627 us; speedup vs baseline: 2.1237x; 1.2585x over previous
//
#include <hip/hip_runtime.h>
#include <hip/hip_bf16.h>
#include <cstdint>
#include <cstddef>

// SlideAttention fused pipeline for MI355X (gfx950).
// B=8, H=W=64, C=256, HEADS=8, U=32, WIN=3 (9 taps), CPB=512.
//
// R10 = (c, c+16) channel-pair k_attn:
//   lane owns channels (c, c+16) of one head -> fdot2 sums the pair,
//   reduction is 16 lanes / 4 DPP stages (no ds_swizzle), logit work
//   replicated 16-wide (was 32), conv weights are true pairs (no splat).
//   att stored pair-permuted; pT built with inverse permutation.

typedef __attribute__((ext_vector_type(4))) float f32x4;
typedef __attribute__((ext_vector_type(8))) short s16x8;
typedef __attribute__((ext_vector_type(4))) int   i32x4;
typedef _Float16 h2 __attribute__((ext_vector_type(2)));

#define DEVINL __device__ __forceinline__

DEVINL unsigned short f2bf(float f) {  // RNE, finite inputs only
    unsigned int u = __builtin_bit_cast(unsigned int, f);
    u += 0x7FFFu + ((u >> 16) & 1u);
    return (unsigned short)(u >> 16);
}
// LDS xor-swizzle for GEMM tiles (rows 128 B)
DEVINL int swz(int off) { return off ^ ((off >> 3) & 0x70); }

DEVINL float fexp2(float x) {
#if __has_builtin(__builtin_amdgcn_exp2f)
    return __builtin_amdgcn_exp2f(x);
#else
    return exp2f(x);
#endif
}
DEVINL float fdot2f(h2 a, h2 b, float c) {
#if __has_builtin(__builtin_amdgcn_fdot2)
    return __builtin_amdgcn_fdot2(a, b, c, false);
#else
    return fmaf((float)a.x, (float)b.x, fmaf((float)a.y, (float)b.y, c));
#endif
}

// ---------------------------------------------------------------- setup ----
__global__ void k_setup(const float* __restrict__ scale,
                        const float* __restrict__ w1,
                        const float* __restrict__ b1,
                        const float* __restrict__ w2,
                        float* __restrict__ relb,
                        float* __restrict__ escale) {
    __shared__ float hbuf[512 * 9];
    __shared__ float part[8][72];
    const float LOG2E = 1.4426950408889634f;
    const int t = threadIdx.x;
    if (t < 512) {
        float wa = w1[t], wb = w1[512 + t], bb = b1[t];
        #pragma unroll
        for (int m = 0; m < 9; ++m) {
            float dy = (float)(m / 3 - 1), dx = (float)(m % 3 - 1);
            const float il8 = 0.48089834696298783f; // 1/ln(8)
            float r0 = (dy > 0.f ? 1.f : (dy < 0.f ? -1.f : 0.f)) * log1pf(fabsf(dy)) * il8;
            float r1 = (dx > 0.f ? 1.f : (dx < 0.f ? -1.f : 0.f)) * log1pf(fabsf(dx)) * il8;
            hbuf[t * 9 + m] = fmaxf(r0 * wa + r1 * wb + bb, 0.f);
        }
    }
    __syncthreads();
    {
        int chunk = t / 72, mh = t % 72;
        int m = mh / 8, head = mh % 8;
        float acc = 0.f;
        #pragma unroll 8
        for (int j = chunk * 64; j < chunk * 64 + 64; ++j)
            acc = fmaf(hbuf[j * 9 + m], w2[j * 8 + head], acc);
        part[chunk][mh] = acc;
    }
    __syncthreads();
    if (t < 72) {
        int m = t / 8, head = t % 8;
        float acc = 0.f;
        #pragma unroll
        for (int ch = 0; ch < 8; ++ch) acc += part[ch][t];
        relb[head * 9 + m] = 16.f / (1.f + expf(-acc)) * LOG2E;  // log2-domain
    } else if (t < 80) {
        escale[t - 72] = expf(scale[t - 72]) * LOG2E;            // log2-domain
    }
}

// ------------------------------------------------------------ transpose ----
// dkw2[l*128+pr] = (f16 dk[tap][c][m], f16 dk[tap][c+16][m]),
//   l = tap*9+m, c = (pr>>4)*32 + (pr&15).
// pT permuted to match the pair-ordered att layout.
__global__ void k_transpose(const float* __restrict__ dk,
                            const float* __restrict__ wq,
                            const float* __restrict__ pw,
                            unsigned int* __restrict__ dkw2,
                            unsigned short* __restrict__ wT,
                            unsigned short* __restrict__ pT) {
    int i = blockIdx.x * blockDim.x + threadIdx.x;
    if (i < 10368) {
        int l = i >> 7, pr = i & 127;
        int tap = l / 9, m = l % 9;
        int c = (pr >> 4) * 32 + (pr & 15);
        float f0 = dk[(tap * 256 + c) * 9 + m];
        float f1 = dk[(tap * 256 + c + 16) * 9 + m];
        unsigned short h0 = __builtin_bit_cast(unsigned short, (_Float16)f0);
        unsigned short h1 = __builtin_bit_cast(unsigned short, (_Float16)f1);
        dkw2[i] = (unsigned int)h0 | ((unsigned int)h1 << 16);
        return;
    }
    int j = i - 10368;
    if (j < 196608) {                   // wT[n*256+k] = bf16(wq[k*768+n])
        int n = j >> 8, k = j & 255;
        wT[j] = f2bf(wq[k * 768 + n]);
        return;
    }
    int p = j - 196608;
    if (p < 65536) {   // pT[n*256+kp] = f16(pw[c(kp)*256+n]), pair-permuted K
        int n = p >> 8, kp = p & 255;
        int head = kp >> 5, tt = kp & 31, ci = tt >> 1, jj = tt & 1;
        int c = head * 32 + ci + 16 * jj;
        pT[p] = __builtin_bit_cast(unsigned short, (_Float16)pw[c * 256 + n]);
    }
}

// ------------------------------------------------------------- qkv GEMM ----
// 768 blocks; XCD-chunked so the 3 N-tiles of one M-tile land on one XCD L2.
__launch_bounds__(512, 1)
__global__ void k_qkv_gemm(const float* __restrict__ x,
                           const unsigned short* __restrict__ wT,
                           const float* __restrict__ qb,
                           const float* __restrict__ vb,
                           unsigned short* __restrict__ qkv) {
    __shared__ __align__(16) unsigned short As[128 * 64];
    __shared__ __align__(16) unsigned short Bs[256 * 64];
    const int orig = blockIdx.x;
    const int tile = (orig & 7) * 96 + (orig >> 3);   // 768 = 8 XCD x 96
    const int m0 = (tile / 3) * 128;
    const int n0 = (tile % 3) * 256;
    const int t = threadIdx.x;
    const int wid = t >> 6, lane = t & 63;
    const int wm = wid >> 2, wn = wid & 3;
    const int lr = lane & 15, lk = lane >> 4;
    const int ar = t >> 2, aq = t & 3;
    const int bn = t >> 1, bh = t & 1;
    f32x4 acc[4][4] = {};

    for (int ks = 0; ks < 256; ks += 64) {
        {   // stage A (f32 -> bf16)
            const float* src = x + (size_t)(m0 + ar) * 256 + ks + aq * 16;
            f32x4 v0 = *(const f32x4*)(src + 0);
            f32x4 v1 = *(const f32x4*)(src + 4);
            f32x4 v2 = *(const f32x4*)(src + 8);
            f32x4 v3 = *(const f32x4*)(src + 12);
            s16x8 h0, h1;
            h0[0]=(short)f2bf(v0[0]); h0[1]=(short)f2bf(v0[1]); h0[2]=(short)f2bf(v0[2]); h0[3]=(short)f2bf(v0[3]);
            h0[4]=(short)f2bf(v1[0]); h0[5]=(short)f2bf(v1[1]); h0[6]=(short)f2bf(v1[2]); h0[7]=(short)f2bf(v1[3]);
            h1[0]=(short)f2bf(v2[0]); h1[1]=(short)f2bf(v2[1]); h1[2]=(short)f2bf(v2[2]); h1[3]=(short)f2bf(v2[3]);
            h1[4]=(short)f2bf(v3[0]); h1[5]=(short)f2bf(v3[1]); h1[6]=(short)f2bf(v3[2]); h1[7]=(short)f2bf(v3[3]);
            int off = ar * 128 + aq * 32;
            *(s16x8*)((char*)As + swz(off))      = h0;
            *(s16x8*)((char*)As + swz(off + 16)) = h1;
        }
        {   // stage B (already bf16, K-major)
            const unsigned short* src = wT + (size_t)(n0 + bn) * 256 + ks + bh * 32;
            s16x8 b0 = *(const s16x8*)(src + 0);
            s16x8 b1 = *(const s16x8*)(src + 8);
            s16x8 b2 = *(const s16x8*)(src + 16);
            s16x8 b3 = *(const s16x8*)(src + 24);
            int off = bn * 128 + bh * 64;
            *(s16x8*)((char*)Bs + swz(off))      = b0;
            *(s16x8*)((char*)Bs + swz(off + 16)) = b1;
            *(s16x8*)((char*)Bs + swz(off + 32)) = b2;
            *(s16x8*)((char*)Bs + swz(off + 48)) = b3;
        }
        __syncthreads();
        #pragma unroll
        for (int kc = 0; kc < 2; ++kc) {
            s16x8 af[4], bfr[4];
            #pragma unroll
            for (int i = 0; i < 4; ++i) {
                int off = (wm * 64 + i * 16 + lr) * 128 + kc * 64 + lk * 16;
                af[i] = *(const s16x8*)((const char*)As + swz(off));
            }
            #pragma unroll
            for (int i = 0; i < 4; ++i) {
                int off = (wn * 64 + i * 16 + lr) * 128 + kc * 64 + lk * 16;
                bfr[i] = *(const s16x8*)((const char*)Bs + swz(off));
            }
            #pragma unroll
            for (int i = 0; i < 4; ++i)
                #pragma unroll
                for (int j = 0; j < 4; ++j)
                    acc[i][j] = __builtin_amdgcn_mfma_f32_16x16x32_bf16(af[i], bfr[j], acc[i][j], 0, 0, 0);
        }
        __syncthreads();
    }
    #pragma unroll
    for (int i = 0; i < 4; ++i) {
        const int mg = m0 + wm * 64 + i * 16 + lk * 4;
        #pragma unroll
        for (int j = 0; j < 4; ++j) {
            const int ng = n0 + wn * 64 + j * 16 + lr;
            float bias = (ng < 256) ? qb[ng] : ((ng < 512) ? 0.f : vb[ng - 512]);
            #pragma unroll
            for (int e = 0; e < 4; ++e)
                qkv[(size_t)(mg + e) * 768 + ng] =
                    __builtin_bit_cast(unsigned short, (_Float16)(acc[i][j][e] + bias));
        }
    }
}

// ------------------------------------------------- fused conv + attention ----
// Lane owns channel pair (c, c+16), c = head*32 + ci.  16 lanes per
// (head, pixel); 2 pixels concurrent (g = t>>7); 8 iterations for 16 px.
// Conv: v_pk_fma_f16 with true weight pairs. Products: fdot2 (sums pair).
// Reduce: 16 lanes, 4 DPP stages only.

template <int CTRL>
DEVINL float dpp_add(float x) {
    int r = __builtin_amdgcn_update_dpp(0, __builtin_bit_cast(int, x),
                                        CTRL, 0xF, 0xF, true);
    return x + __builtin_bit_cast(float, r);
}
DEVINL float red16(float x) {
    x = dpp_add<0xB1>(x);   // quad_perm [1,0,3,2]  : xor1
    x = dpp_add<0x4E>(x);   // quad_perm [2,3,0,1]  : xor2
    x = dpp_add<0x141>(x);  // row_half_mirror      : 8-group
    x = dpp_add<0x140>(x);  // row_mirror           : 16-group
    return x;
}

__launch_bounds__(256, 1)
__global__ void k_attn(const unsigned short* __restrict__ qkv,
                       const unsigned int* __restrict__ dkw2,
                       const float* __restrict__ relb,
                       const float* __restrict__ escale,
                       unsigned short* __restrict__ att) {
    __shared__ __align__(16) unsigned int ksh[36 * 128];  // k pairs (c, c+16)
    __shared__ __align__(16) unsigned int vsh[36 * 128];  // v pairs
    __shared__ __align__(16) unsigned int qsh[16 * 128];  // q pairs
    const int t = threadIdx.x;
    const int g = t >> 7;          // pixel half
    const int pr = t & 127;        // pair index = head*16 + ci
    const int head = pr >> 4;
    const int w0 = blockIdx.x * 4, h0 = blockIdx.y * 4, b = blockIdx.z;

    unsigned int wk[81];           // weight pairs (w_c, w_c+16) per l=ij*9+m
    #pragma unroll
    for (int l = 0; l < 81; ++l) wk[l] = dkw2[l * 128 + pr];
    float rb[9];
    #pragma unroll
    for (int m = 0; m < 9; ++m) rb[m] = relb[head * 9 + m];
    const float es2 = escale[head];          // exp(scale)*log2e

    // stage k/v halo pairs: 36 px x 16 units (unit = data-head*2 + half)
    for (int idx = t; idx < 576; idx += 256) {
        int hp = idx >> 4, u = idx & 15;
        int hh = u >> 1, half = u & 1;
        int cA = hh * 32 + half * 8;
        int hy = h0 - 1 + hp / 6, hx = w0 - 1 + hp % 6;
        i32x4 kA = {0,0,0,0}, kB = {0,0,0,0}, vA = {0,0,0,0}, vB = {0,0,0,0};
        if ((unsigned)hy < 64u && (unsigned)hx < 64u) {
            const unsigned short* base = qkv + ((size_t)((b * 64 + hy) * 64 + hx)) * 768;
            kA = *(const i32x4*)(base + 256 + cA);
            kB = *(const i32x4*)(base + 256 + cA + 16);
            vA = *(const i32x4*)(base + 512 + cA);
            vB = *(const i32x4*)(base + 512 + cA + 16);
        }
        i32x4 kp0, kp1, vp0, vp1;
        #pragma unroll
        for (int e = 0; e < 4; ++e) {
            unsigned klo = __builtin_amdgcn_perm((unsigned)kB[e], (unsigned)kA[e], 0x05040100u);
            unsigned khi = __builtin_amdgcn_perm((unsigned)kB[e], (unsigned)kA[e], 0x07060302u);
            unsigned vlo = __builtin_amdgcn_perm((unsigned)vB[e], (unsigned)vA[e], 0x05040100u);
            unsigned vhi = __builtin_amdgcn_perm((unsigned)vB[e], (unsigned)vA[e], 0x07060302u);
            if (e < 2) {
                kp0[2*e] = (int)klo; kp0[2*e+1] = (int)khi;
                vp0[2*e] = (int)vlo; vp0[2*e+1] = (int)vhi;
            } else {
                kp1[2*(e-2)] = (int)klo; kp1[2*(e-2)+1] = (int)khi;
                vp1[2*(e-2)] = (int)vlo; vp1[2*(e-2)+1] = (int)vhi;
            }
        }
        int pi = hp * 128 + hh * 16 + half * 8;
        *(i32x4*)(ksh + pi)     = kp0;
        *(i32x4*)(ksh + pi + 4) = kp1;
        *(i32x4*)(vsh + pi)     = vp0;
        *(i32x4*)(vsh + pi + 4) = vp1;
    }
    // stage q pairs: exactly one unit per thread (16 px x 16 units)
    {
        int px_s = t >> 4, u = t & 15;
        int hh = u >> 1, half = u & 1;
        int cA = hh * 32 + half * 8;
        int iy = h0 + (px_s >> 2), ix = w0 + (px_s & 3);
        const unsigned short* base = qkv + ((size_t)((b * 64 + iy) * 64 + ix)) * 768;
        i32x4 qA = *(const i32x4*)(base + cA);
        i32x4 qB = *(const i32x4*)(base + cA + 16);
        i32x4 qp0, qp1;
        #pragma unroll
        for (int e = 0; e < 4; ++e) {
            unsigned lo = __builtin_amdgcn_perm((unsigned)qB[e], (unsigned)qA[e], 0x05040100u);
            unsigned hi = __builtin_amdgcn_perm((unsigned)qB[e], (unsigned)qA[e], 0x07060302u);
            if (e < 2) { qp0[2*e] = (int)lo; qp0[2*e+1] = (int)hi; }
            else       { qp1[2*(e-2)] = (int)lo; qp1[2*(e-2)+1] = (int)hi; }
        }
        int pi = px_s * 128 + hh * 16 + half * 8;
        *(i32x4*)(qsh + pi)     = qp0;
        *(i32x4*)(qsh + pi + 4) = qp1;
    }
    __syncthreads();

    #pragma unroll 1
    for (int it = 0; it < 8; ++it) {
        const int p = it * 2 + g;
        const int py = p >> 2, px = p & 3;
        const int iy = h0 + py, ix = w0 + px;
        const size_t pix = (size_t)((b * 64 + iy) * 64 + ix);
        const h2 q2 = __builtin_bit_cast(h2, qsh[p * 128 + pr]);

        h2 ki[9], vi[9];
        #pragma unroll
        for (int ij = 0; ij < 9; ++ij) {
            int hp = (py + ij / 3) * 6 + (px + ij % 3);
            ki[ij] = __builtin_bit_cast(h2, ksh[hp * 128 + pr]);
            vi[ij] = __builtin_bit_cast(h2, vsh[hp * 128 + pr]);
        }
        h2 ka[9], va[9];
        #pragma unroll
        for (int m = 0; m < 9; ++m) { ka[m] = ki[m]; va[m] = vi[m]; }  // identity tap
        #pragma unroll
        for (int ij = 0; ij < 9; ++ij)
            #pragma unroll
            for (int m = 0; m < 9; ++m)
                if (ij != m) {
                    h2 w = __builtin_bit_cast(h2, wk[ij * 9 + m]);
                    ka[m] = __builtin_elementwise_fma(ki[ij], w, ka[m]);
                    va[m] = __builtin_elementwise_fma(vi[ij], w, va[m]);
                }

        float red[19];
        red[0] = fdot2f(q2, q2, 0.f);
        #pragma unroll
        for (int m = 0; m < 9; ++m) {
            red[1 + m]  = fdot2f(q2, ka[m], 0.f);
            red[10 + m] = fdot2f(ka[m], ka[m], 0.f);
        }
        #pragma unroll
        for (int i = 0; i < 19; ++i) red[i] = red16(red[i]);

        const float rq = __builtin_amdgcn_rsqf(fmaxf(red[0], 1.55e-5f)) * es2;
        const bool yt = (iy == 0), yb = (iy == 63), xl = (ix == 0), xr = (ix == 63);
        const float NEG = -144.2695040888963f;  // -100*log2e
        float e[9], sum = 0.f;
        #pragma unroll
        for (int m = 0; m < 9; ++m) {
            float rk = __builtin_amdgcn_rsqf(fmaxf(red[10 + m], 1.55e-5f));
            int dy = m / 3 - 1, dx = m % 3 - 1;
            bool oob = (dy < 0 && yt) || (dy > 0 && yb) || (dx < 0 && xl) || (dx > 0 && xr);
            float a = red[1 + m] * rq * rk + rb[m] + (oob ? NEG : 0.f);
            e[m] = fexp2(a);            // f32: range-safe without max-subtract
            sum += e[m];
        }
        const float rs = __builtin_amdgcn_rcpf(sum);
        h2 o2 = {(_Float16)0.f, (_Float16)0.f};
        #pragma unroll
        for (int m = 0; m < 9; ++m) {
            _Float16 ph = (_Float16)(e[m] * rs);   // p in [0,1] -> f16 safe
            h2 pb2 = {ph, ph};
            o2 = __builtin_elementwise_fma(va[m], pb2, o2);
        }
        // pair-ordered att row: dword pr holds (att_c, att_c+16)
        *(unsigned int*)(att + pix * 256 + pr * 2) = __builtin_bit_cast(unsigned int, o2);
    }
}

// ------------------------------------------------------------- proj GEMM ----
__launch_bounds__(512, 1)
__global__ void k_proj_gemm(const unsigned short* __restrict__ attin,
                            const unsigned short* __restrict__ pT,
                            const float* __restrict__ pb,
                            float* __restrict__ out) {
    __shared__ __align__(16) unsigned short As[128 * 64];
    __shared__ __align__(16) unsigned short Bs[256 * 64];
    const int t = threadIdx.x;
    const int m0 = blockIdx.x * 128;
    const int wid = t >> 6, lane = t & 63;
    const int wm = wid >> 2, wn = wid & 3;
    const int lr = lane & 15, lk = lane >> 4;
    const int ar = t >> 2, aq = t & 3;
    const int bn = t >> 1, bh = t & 1;
    f32x4 acc[4][4] = {};

    for (int ks = 0; ks < 256; ks += 64) {
        {   // stage A (f16 rows of att, pair-permuted K — matches pT)
            const unsigned short* src = attin + (size_t)(m0 + ar) * 256 + ks + aq * 16;
            s16x8 h0 = *(const s16x8*)(src + 0);
            s16x8 h1 = *(const s16x8*)(src + 8);
            int off = ar * 128 + aq * 32;
            *(s16x8*)((char*)As + swz(off))      = h0;
            *(s16x8*)((char*)As + swz(off + 16)) = h1;
        }
        {   // stage B (f16)
            const unsigned short* src = pT + (size_t)bn * 256 + ks + bh * 32;
            s16x8 b0 = *(const s16x8*)(src + 0);
            s16x8 b1 = *(const s16x8*)(src + 8);
            s16x8 b2 = *(const s16x8*)(src + 16);
            s16x8 b3 = *(const s16x8*)(src + 24);
            int off = bn * 128 + bh * 64;
            *(s16x8*)((char*)Bs + swz(off))      = b0;
            *(s16x8*)((char*)Bs + swz(off + 16)) = b1;
            *(s16x8*)((char*)Bs + swz(off + 32)) = b2;
            *(s16x8*)((char*)Bs + swz(off + 48)) = b3;
        }
        __syncthreads();
        #pragma unroll
        for (int kc = 0; kc < 2; ++kc) {
            s16x8 af[4], bfr[4];
            #pragma unroll
            for (int i = 0; i < 4; ++i) {
                int off = (wm * 64 + i * 16 + lr) * 128 + kc * 64 + lk * 16;
                af[i] = *(const s16x8*)((const char*)As + swz(off));
            }
            #pragma unroll
            for (int i = 0; i < 4; ++i) {
                int off = (wn * 64 + i * 16 + lr) * 128 + kc * 64 + lk * 16;
                bfr[i] = *(const s16x8*)((const char*)Bs + swz(off));
            }
            #pragma unroll
            for (int i = 0; i < 4; ++i)
                #pragma unroll
                for (int j = 0; j < 4; ++j)
                    acc[i][j] = __builtin_amdgcn_mfma_f32_16x16x32_f16(af[i], bfr[j], acc[i][j], 0, 0, 0);
        }
        __syncthreads();
    }
    #pragma unroll
    for (int i = 0; i < 4; ++i) {
        const int mg = m0 + wm * 64 + i * 16 + lk * 4;
        #pragma unroll
        for (int j = 0; j < 4; ++j) {
            const int ng = wn * 64 + j * 16 + lr;
            const float bias = pb[ng];
            #pragma unroll
            for (int e = 0; e < 4; ++e)
                out[(size_t)(mg + e) * 256 + ng] = acc[i][j][e] + bias;
        }
    }
}

// ----------------------------------------------------------------- launch ----
extern "C" void kernel_launch(void* const* d_in, const int* in_sizes, int n_in,
                              void* d_out, int out_size, void* d_ws, size_t ws_size,
                              hipStream_t stream) {
    const float* x  = (const float*)d_in[0];
    const float* wq = (const float*)d_in[1];
    const float* qb = (const float*)d_in[2];
    const float* vb = (const float*)d_in[3];
    const float* dk = (const float*)d_in[4];
    const float* sc = (const float*)d_in[5];
    const float* w1 = (const float*)d_in[6];
    const float* b1 = (const float*)d_in[7];
    const float* w2 = (const float*)d_in[8];
    const float* pw = (const float*)d_in[9];
    const float* pb = (const float*)d_in[10];
    float* out = (float*)d_out;

    char* ws = (char*)d_ws;
    unsigned short* qkv  = (unsigned short*)(ws + 0);          // 50,331,648 B (f16)
    unsigned short* att  = (unsigned short*)(ws + 50331648);   // 16,777,216 B (f16, pair-order)
    unsigned int*   dkw2 = (unsigned int*)(ws + 67108864);     //     41,472 B
    unsigned short* wT   = (unsigned short*)(ws + 67150336);   //    393,216 B (bf16)
    unsigned short* pT   = (unsigned short*)(ws + 67543552);   //    131,072 B (f16, permuted)
    float*          rlb  = (float*)(ws + 67674624);            //        288 B
    float*          esc  = (float*)(ws + 67674912);            //         32 B

    hipLaunchKernelGGL(k_setup, dim3(1), dim3(576), 0, stream, sc, w1, b1, w2, rlb, esc);
    hipLaunchKernelGGL(k_transpose, dim3(1065), dim3(256), 0, stream, dk, wq, pw, dkw2, wT, pT);
    hipLaunchKernelGGL(k_qkv_gemm, dim3(768), dim3(512), 0, stream, x, wT, qb, vb, qkv);
    hipLaunchKernelGGL(k_attn, dim3(16, 16, 8), dim3(256), 0, stream, qkv, dkw2, rlb, esc, att);
    hipLaunchKernelGGL(k_proj_gemm, dim3(256), dim3(512), 0, stream, att, pT, pb, out);
}